// Round 20
// baseline (1780.286 us; speedup 1.0000x reference)
//
#include <hip/hip_runtime.h>
#include <hip/hip_fp16.h>
#include <math.h>

typedef __attribute__((ext_vector_type(8))) short short8;
typedef __attribute__((ext_vector_type(4))) float f32x4;
typedef unsigned short u16;

#define NTOK 841
#define GRID_H 29
#define E_ 384
#define NH_ 6
#define MROWS 13456
#define MP 13568
#define MQ 14336
#define CM 5120

__device__ __forceinline__ u16 f2bf(float f) {
  union { float f; unsigned int u; } c; c.f = f;
  unsigned int u = c.u;
  return (u16)((u + 0x7fffu + ((u >> 16) & 1u)) >> 16);
}

__device__ __forceinline__ float bf2f(u16 b) {
  union { unsigned int u; float f; } c; c.u = ((unsigned int)b) << 16; return c.f;
}

__device__ __forceinline__ float gelu_exact(float v) {
  return 0.5f * v * (1.f + erff(v * 0.70710678118654752440f));
}

__device__ __forceinline__ float fexp2(float x) {
  float r; asm("v_exp_f32 %0, %1" : "=v"(r) : "v"(x)); return r;
}

// byte offset in a [rows][64]-bf16 tile (128B/row), 16B-chunk XOR swizzle
__device__ __forceinline__ int swz64(int row, int col) {
  return row * 128 + ((((col >> 3) ^ (row & 7)) << 4) | ((col & 7) << 1));
}

// ---------------- transpose + fp32->bf16 convert: in [K][N] -> out [N][K] ----
__global__ __launch_bounds__(256) void transpose_conv(const float* __restrict__ in,
    u16* __restrict__ out, int K, int N) {
  __shared__ float tile[32][33];
  size_t zo = (size_t)blockIdx.z * K * N;
  const float* inp = in + zo;
  u16* outp = out + zo;
  int n0 = blockIdx.x * 32, k0 = blockIdx.y * 32;
  int tx = threadIdx.x & 31, ty = threadIdx.x >> 5;
  #pragma unroll
  for (int r = ty; r < 32; r += 8) tile[r][tx] = inp[(size_t)(k0 + r) * N + n0 + tx];
  __syncthreads();
  #pragma unroll
  for (int r = ty; r < 32; r += 8) outp[(size_t)(n0 + r) * K + k0 + tx] = f2bf(tile[tx][r]);
}

// ---------------- fused 5-shift patchify + LayerNorm(3840) -> bf16 ----------
__global__ __launch_bounds__(256) void patch_ln(const float* __restrict__ x,
    const float* __restrict__ g, const float* __restrict__ bsh, u16* __restrict__ out,
    int t0) {
  int t = t0 + blockIdx.x;
  int tid = threadIdx.x;
  u16* orow = out + (size_t)blockIdx.x * 3840;
  if (t >= MROWS) {
    #pragma unroll
    for (int j = 0; j < 15; ++j) orow[tid + j * 256] = 0;  // bf16 zero
    return;
  }
  int bimg = t / NTOK, n = t % NTOK;
  int gy = n / GRID_H, gx = n % GRID_H;
  float vals[15];
  float s1 = 0.f, s2 = 0.f;
  #pragma unroll
  for (int j = 0; j < 15; ++j) {
    int cout = tid + j * 256;
    int s = cout / 768, rem = cout % 768;
    int c = rem / 256, rem2 = rem % 256;
    int py = rem2 / 16, px = rem2 % 16;
    int dy = (s == 1 ? 8 : 0) - (s == 2 ? 8 : 0);
    int dx = (s == 3 ? 8 : 0) - (s == 4 ? 8 : 0);
    int Y = gy * 16 + py - dy;
    int X = gx * 16 + px - dx;
    float v = 0.f;
    if (Y >= 0 && Y < 464 && X >= 0 && X < 464)
      v = x[(((size_t)bimg * 3 + c) * 464 + Y) * 464 + X];
    vals[j] = v;
    s1 += v; s2 += v * v;
  }
  #pragma unroll
  for (int m = 1; m < 64; m <<= 1) { s1 += __shfl_xor(s1, m); s2 += __shfl_xor(s2, m); }
  __shared__ float ws1[4], ws2[4];
  int wid = tid >> 6;
  if ((tid & 63) == 0) { ws1[wid] = s1; ws2[wid] = s2; }
  __syncthreads();
  s1 = ws1[0] + ws1[1] + ws1[2] + ws1[3];
  s2 = ws2[0] + ws2[1] + ws2[2] + ws2[3];
  float mean = s1 * (1.f / 3840.f);
  float var = s2 * (1.f / 3840.f) - mean * mean;
  float rs = rsqrtf(var + 1e-5f);
  #pragma unroll
  for (int j = 0; j < 15; ++j) {
    int cout = tid + j * 256;
    orow[cout] = f2bf((vals[j] - mean) * rs * g[cout] + bsh[cout]);
  }
}

// ---------------- LayerNorm(384) fp32 -> bf16 (packed MP rows) ---------------
__global__ __launch_bounds__(256) void ln384(const float* __restrict__ h,
    const float* __restrict__ g, const float* __restrict__ bsh, u16* __restrict__ y) {
  int row = blockIdx.x * 4 + (threadIdx.x >> 6);
  int lane = threadIdx.x & 63;
  const float* hr = h + (size_t)row * E_;
  float v[6];
  float s1 = 0.f;
  #pragma unroll
  for (int j = 0; j < 6; ++j) { v[j] = hr[lane + j * 64]; s1 += v[j]; }
  #pragma unroll
  for (int m = 1; m < 64; m <<= 1) s1 += __shfl_xor(s1, m);
  float mean = s1 * (1.f / 384.f);
  float s2 = 0.f;
  #pragma unroll
  for (int j = 0; j < 6; ++j) { float d = v[j] - mean; s2 += d * d; }
  #pragma unroll
  for (int m = 1; m < 64; m <<= 1) s2 += __shfl_xor(s2, m);
  float rs = rsqrtf(s2 * (1.f / 384.f) + 1e-5f);
  u16* yr = y + (size_t)row * E_;
  #pragma unroll
  for (int j = 0; j < 6; ++j) {
    int c = lane + j * 64;
    yr[c] = f2bf((v[j] - mean) * rs * g[c] + bsh[c]);
  }
}

// ---------------- LayerNorm(384) -> 896-padded bf16 (zeros on pad rows) ------
__global__ __launch_bounds__(256) void ln384p(const float* __restrict__ h,
    const float* __restrict__ g, const float* __restrict__ bsh, u16* __restrict__ yp) {
  int rowp = blockIdx.x * 4 + (threadIdx.x >> 6);
  int lane = threadIdx.x & 63;
  int bg = rowp / 896, tk = rowp - bg * 896;
  u16* yr = yp + (size_t)rowp * E_;
  if (tk >= NTOK) {
    #pragma unroll
    for (int j = 0; j < 6; ++j) yr[lane + j * 64] = 0;
    return;
  }
  const float* hr = h + (size_t)(bg * NTOK + tk) * E_;
  float v[6];
  float s1 = 0.f;
  #pragma unroll
  for (int j = 0; j < 6; ++j) { v[j] = hr[lane + j * 64]; s1 += v[j]; }
  #pragma unroll
  for (int m = 1; m < 64; m <<= 1) s1 += __shfl_xor(s1, m);
  float mean = s1 * (1.f / 384.f);
  float s2 = 0.f;
  #pragma unroll
  for (int j = 0; j < 6; ++j) { float d = v[j] - mean; s2 += d * d; }
  #pragma unroll
  for (int m = 1; m < 64; m <<= 1) s2 += __shfl_xor(s2, m);
  float rs = rsqrtf(s2 * (1.f / 384.f) + 1e-5f);
  #pragma unroll
  for (int j = 0; j < 6; ++j) {
    int c = lane + j * 64;
    yr[c] = f2bf((v[j] - mean) * rs * g[c] + bsh[c]);
  }
}

// ---------------- bf16 MFMA GEMM, min-2-phase pipelined (T3+T4) --------------
// EPI: 1 = bf16 gelu(acc+bias), LDS-staged coalesced out; 2 = f32 acc+bias;
//      3 = resid[m][n] += lscale[n]*(acc+bias[n]);
//      4 = outf[m][n] = resid[m][n] + lscale[n]*(acc+bias[n]) (final, m<MROWS)
// BK: 64 (8-chunk swizzle) or 32 (4-chunk swizzle, halves LDS for occupancy)
template<int EPI, int TM, int BK>
__global__ __launch_bounds__(256) void gemm_bt(
    const u16* __restrict__ A, const u16* __restrict__ BT,
    int N, int K,
    const float* __restrict__ bias, const float* __restrict__ lscale,
    float* __restrict__ resid, u16* __restrict__ outb, float* __restrict__ outf) {
  constexpr int MI = TM / 32;
  constexpr int BUF = (TM + 128) * BK;              // shorts per buffer
  constexpr int SM1 = 2 * BUF * 2;
  constexpr int SM2 = (EPI == 1) ? TM * 136 * 2 : 0;
  constexpr int SMEM = SM1 > SM2 ? SM1 : SM2;
  __shared__ alignas(16) char smem[SMEM];
  short* As = (short*)smem;
  // bijective XCD swizzle (m204)
  const int gx = gridDim.x;
  const int nwg = gx * gridDim.y;
  int L = blockIdx.x + blockIdx.y * gx;
  int q8 = nwg >> 3, r8 = nwg & 7, xcd = L & 7, pos = L >> 3;
  int L2 = (xcd < r8 ? xcd * (q8 + 1) : r8 * (q8 + 1) + (xcd - r8) * q8) + pos;
  const int m0 = (L2 / gx) * TM, n0 = (L2 % gx) * 128;
  const int tid = threadIdx.x;
  const int lane = tid & 63, wid = tid >> 6;
  const int wm = wid >> 1, wn = wid & 1;
  f32x4 acc[MI][4] = {};
  const int nkt = K / BK;

  auto stage = [&](int b, int kt) {
    short* Ab = As + b * BUF;
    short* Bb = Ab + TM * BK;
    const int k0 = kt * BK;
    if constexpr (BK == 64) {
      const int rowl = lane >> 3;
      const int colc = (((lane & 7) ^ (rowl & 7)) << 3);
      #pragma unroll
      for (int i = 0; i < TM / 32; ++i) {
        int chunk = i * 4 + wid;
        const u16* ga = A + (size_t)(m0 + chunk * 8 + rowl) * K + k0 + colc;
        __builtin_amdgcn_global_load_lds((const __attribute__((address_space(1))) void*)ga,
            (__attribute__((address_space(3))) void*)(Ab + (chunk << 9)), 16, 0, 0);
      }
      #pragma unroll
      for (int i = 0; i < 4; ++i) {
        int chunk = i * 4 + wid;
        const u16* gb = BT + (size_t)(n0 + chunk * 8 + rowl) * K + k0 + colc;
        __builtin_amdgcn_global_load_lds((const __attribute__((address_space(1))) void*)gb,
            (__attribute__((address_space(3))) void*)(Bb + (chunk << 9)), 16, 0, 0);
      }
    } else {
      const int rowl = lane >> 2;                 // 16 rows per wave-slab
      const int colc = (((lane & 3) ^ (rowl & 3)) << 3);
      #pragma unroll
      for (int i = 0; i < TM / 64; ++i) {
        int rbase = i * 64 + wid * 16;
        const u16* ga = A + (size_t)(m0 + rbase + rowl) * K + k0 + colc;
        __builtin_amdgcn_global_load_lds((const __attribute__((address_space(1))) void*)ga,
            (__attribute__((address_space(3))) void*)(Ab + rbase * 32), 16, 0, 0);
      }
      #pragma unroll
      for (int i = 0; i < 2; ++i) {
        int rbase = i * 64 + wid * 16;
        const u16* gb = BT + (size_t)(n0 + rbase + rowl) * K + k0 + colc;
        __builtin_amdgcn_global_load_lds((const __attribute__((address_space(1))) void*)gb,
            (__attribute__((address_space(3))) void*)(Bb + rbase * 32), 16, 0, 0);
      }
    }
  };

  const int lg = lane >> 4;
  stage(0, 0);
  for (int kt = 0; kt < nkt; ++kt) {
    const int cur = kt & 1;
    if (kt + 1 < nkt) {
      stage(cur ^ 1, kt + 1);
      // wait own current-tile loads (allow next tile's NL in flight)
      if constexpr (BK == 64) {
        if constexpr (TM == 128) asm volatile("s_waitcnt vmcnt(8)" ::: "memory");
        else                     asm volatile("s_waitcnt vmcnt(6)" ::: "memory");
      } else {
        if constexpr (TM == 128) asm volatile("s_waitcnt vmcnt(4)" ::: "memory");
        else                     asm volatile("s_waitcnt vmcnt(3)" ::: "memory");
      }
    } else {
      asm volatile("s_waitcnt vmcnt(0)" ::: "memory");
    }
    __builtin_amdgcn_s_barrier();       // all waves' current tile complete
    __builtin_amdgcn_sched_barrier(0);
    short* Ab = As + cur * BUF;
    short* Bb = Ab + TM * BK;
    #pragma unroll
    for (int kk = 0; kk < BK / 32; ++kk) {
      short8 a[MI], bfr[4];
      #pragma unroll
      for (int mi = 0; mi < MI; ++mi) {
        int ra = wm * (TM / 2) + mi * 16 + (lane & 15);
        int off = (BK == 64) ? ((((kk << 2) | lg) ^ (ra & 7)) << 3)
                             : ((lg ^ (ra & 3)) << 3);
        a[mi] = *(const short8*)(Ab + ra * BK + off);
      }
      #pragma unroll
      for (int nj = 0; nj < 4; ++nj) {
        int rb = wn * 64 + nj * 16 + (lane & 15);
        int off = (BK == 64) ? ((((kk << 2) | lg) ^ (rb & 7)) << 3)
                             : ((lg ^ (rb & 3)) << 3);
        bfr[nj] = *(const short8*)(Bb + rb * BK + off);
      }
      #pragma unroll
      for (int mi = 0; mi < MI; ++mi)
        #pragma unroll
        for (int nj = 0; nj < 4; ++nj)
          acc[mi][nj] = __builtin_amdgcn_mfma_f32_16x16x32_bf16(a[mi], bfr[nj], acc[mi][nj], 0, 0, 0);
    }
    __builtin_amdgcn_s_barrier();       // reads of 'cur' done before its overwrite
  }
  const int rrow = (lane >> 4) << 2;
  const int ccol = lane & 15;
  if (EPI == 1) {
    // stage C in LDS, write coalesced full rows
    u16* Cs = (u16*)smem;
    __syncthreads();
    #pragma unroll
    for (int mi = 0; mi < MI; ++mi)
      #pragma unroll
      for (int nj = 0; nj < 4; ++nj) {
        int cc = wn * 64 + nj * 16 + ccol;
        float bi = bias[n0 + cc];
        #pragma unroll
        for (int r = 0; r < 4; ++r) {
          int cr = wm * (TM / 2) + mi * 16 + rrow + r;
          Cs[cr * 136 + cc] = f2bf(gelu_exact(acc[mi][nj][r] + bi));
        }
      }
    __syncthreads();
    #pragma unroll
    for (int it = 0; it < TM / 16; ++it) {
      int idx = it * 256 + tid;
      int orow = idx >> 4, c = idx & 15;
      short8 v = *(const short8*)(Cs + orow * 136 + c * 8);
      *(short8*)(outb + (size_t)(m0 + orow) * N + n0 + c * 8) = v;
    }
    return;
  }
  #pragma unroll
  for (int mi = 0; mi < MI; ++mi)
    #pragma unroll
    for (int nj = 0; nj < 4; ++nj) {
      int gn = n0 + wn * 64 + nj * 16 + ccol;
      #pragma unroll
      for (int r = 0; r < 4; ++r) {
        int gm = m0 + wm * (TM / 2) + mi * 16 + rrow + r;
        float v = acc[mi][nj][r];
        if (EPI == 2) {
          outf[(size_t)gm * N + gn] = v + bias[gn];
        } else if (EPI == 3) {
          float* p = resid + (size_t)gm * N + gn;
          *p = *p + lscale[gn] * (v + bias[gn]);
        } else {
          if (gm < MROWS)
            outf[(size_t)gm * N + gn] =
                resid[(size_t)gm * N + gn] + lscale[gn] * (v + bias[gn]);
        }
      }
    }
}

// ---------------- qkv GEMM over padded-896 rows, pipelined, swizzled out -----
__global__ __launch_bounds__(256) void gemm_qkv(
    const u16* __restrict__ A, const u16* __restrict__ BT,
    u16* __restrict__ Qp, u16* __restrict__ Kp, u16* __restrict__ Vp) {
  const int K = 384;
  constexpr int BUF = 256 * 64;
  __shared__ alignas(16) char smem[2 * BUF * 2];   // 64KB dbuf; Cs aliases
  short* As = (short*)smem;
  // XCD swizzle over 1008 blocks (1008 = 8*126)
  int L = blockIdx.x + blockIdx.y * 9;
  int L2 = (L & 7) * 126 + (L >> 3);
  const int m0 = (L2 / 9) * 128, n0 = (L2 % 9) * 128;
  const int tid = threadIdx.x;
  const int lane = tid & 63, wid = tid >> 6;
  const int wm = wid >> 1, wn = wid & 1;
  const int rowl = lane >> 3;
  const int colc = (((lane & 7) ^ (rowl & 7)) << 3);
  f32x4 acc[4][4] = {};

  auto stage = [&](int b, int kt) {
    short* Ab = As + b * BUF;
    short* Bb = Ab + 128 * 64;
    const int k0 = kt * 64;
    #pragma unroll
    for (int i = 0; i < 4; ++i) {
      int chunk = i * 4 + wid;
      const u16* ga = A + (size_t)(m0 + chunk * 8 + rowl) * K + k0 + colc;
      __builtin_amdgcn_global_load_lds((const __attribute__((address_space(1))) void*)ga,
          (__attribute__((address_space(3))) void*)(Ab + (chunk << 9)), 16, 0, 0);
      const u16* gb = BT + (size_t)(n0 + chunk * 8 + rowl) * K + k0 + colc;
      __builtin_amdgcn_global_load_lds((const __attribute__((address_space(1))) void*)gb,
          (__attribute__((address_space(3))) void*)(Bb + (chunk << 9)), 16, 0, 0);
    }
  };

  stage(0, 0);
  for (int kt = 0; kt < 6; ++kt) {
    const int cur = kt & 1;
    if (kt + 1 < 6) {
      stage(cur ^ 1, kt + 1);
      asm volatile("s_waitcnt vmcnt(8)" ::: "memory");
    } else {
      asm volatile("s_waitcnt vmcnt(0)" ::: "memory");
    }
    __builtin_amdgcn_s_barrier();
    __builtin_amdgcn_sched_barrier(0);
    short* Ab = As + cur * BUF;
    short* Bb = Ab + 128 * 64;
    #pragma unroll
    for (int kk = 0; kk < 2; ++kk) {
      short8 a[4], bfr[4];
      #pragma unroll
      for (int mi = 0; mi < 4; ++mi) {
        int ra = wm * 64 + mi * 16 + (lane & 15);
        a[mi] = *(const short8*)(Ab + ra * 64 + ((((kk << 2) | (lane >> 4)) ^ (ra & 7)) << 3));
      }
      #pragma unroll
      for (int nj = 0; nj < 4; ++nj) {
        int rb = wn * 64 + nj * 16 + (lane & 15);
        bfr[nj] = *(const short8*)(Bb + rb * 64 + ((((kk << 2) | (lane >> 4)) ^ (rb & 7)) << 3));
      }
      #pragma unroll
      for (int mi = 0; mi < 4; ++mi)
        #pragma unroll
        for (int nj = 0; nj < 4; ++nj)
          acc[mi][nj] = __builtin_amdgcn_mfma_f32_16x16x32_bf16(a[mi], bfr[nj], acc[mi][nj], 0, 0, 0);
    }
    __builtin_amdgcn_s_barrier();
  }
  // epilogue: stage in LDS ([tok][col] for Q/K, transposed [col][tok] for V)
  const int seg = n0 / 384;                 // 0=Q 1=K 2=V (block-uniform)
  const int h0 = (n0 - seg * 384) >> 6;     // head pair base: 0,2,4
  const int bg = m0 / 896;
  const int tk0 = m0 - bg * 896;            // 0..768, 64-tile aligned
  const int rrow = (lane >> 4) << 2;
  const int ccol = lane & 15;
  u16* Cs = (u16*)smem;
  __syncthreads();
  #pragma unroll
  for (int mi = 0; mi < 4; ++mi)
    #pragma unroll
    for (int nj = 0; nj < 4; ++nj) {
      int cc = wn * 64 + nj * 16 + ccol;
      #pragma unroll
      for (int r = 0; r < 4; ++r) {
        int cr = wm * 64 + mi * 16 + rrow + r;
        u16 bv = f2bf(acc[mi][nj][r]);
        if (seg == 2) Cs[cc * 136 + cr] = bv;
        else          Cs[cr * 136 + cc] = bv;
      }
    }
  __syncthreads();
  // write out 256 rows x 128B, full-line short8 stores
  #pragma unroll
  for (int i = 0; i < 8; ++i) {
    int idx = i * 256 + tid;
    int c = idx & 7;                 // 16B chunk within 128B row
    int orow = idx >> 3;             // 0..255
    int hs = orow >> 7;              // head select
    int rl = orow & 127;
    size_t bh = (size_t)(bg * 6 + h0 + hs);
    if (seg == 2) {
      int tile_l = rl >> 6, hd = rl & 63;
      short8 v = *(const short8*)(Cs + (hs * 64 + hd) * 136 + tile_l * 64 + c * 8);
      int tile = (tk0 >> 6) + tile_l;
      *(short8*)(Vp + bh * 57344 + tile * 4096 + hd * 64 + ((c ^ (hd & 7)) << 3)) = v;
    } else {
      short8 v = *(const short8*)(Cs + rl * 136 + hs * 64 + c * 8);
      if (seg == 0) {
        *(short8*)(Qp + (bh * 896 + tk0 + rl) * 64 + c * 8) = v;
      } else {
        int tok = tk0 + rl;
        *(short8*)(Kp + bh * 57344 + (tok >> 6) * 4096 + (tok & 63) * 64 + ((c ^ (tok & 7)) << 3)) = v;
      }
    }
  }
}

// ---------------- single-pass flash attention, 8 waves / 128 q-rows ----------
// f16 coord LUT -> 52.7KB LDS -> 3 blocks/CU (single residency round @672 blocks)
__global__ __launch_bounds__(512) void attn_sp(const u16* __restrict__ Qp,
    const u16* __restrict__ Kp, const u16* __restrict__ Vp,
    const float* __restrict__ temp_d, const float* __restrict__ locw_d,
    u16* __restrict__ ob) {
  // 1D grid = hardware dispatch order; bijective XCD swizzle: 672 = 8*84.
  int Lw = blockIdx.x;
  int L2 = (Lw & 7) * 84 + (Lw >> 3);
  const int bh = L2 / 7, qp = L2 % 7;       // qp = 128-row q-block
  const int hh = bh % NH_;
  const int tid = threadIdx.x, lane = tid & 63, w = tid >> 6;   // w in [0,8)
  const int lg = lane >> 4, lc = lane & 15;
  const float LOG2E = 1.44269504088896f;
  const float scale = __expf(temp_d[hh]) * LOG2E;   // exp2-domain
  const float lwh = locw_d[hh] * LOG2E * -0.5f;

  __shared__ alignas(16) char ktl[2][8192];       // K tiles [tok][hd], swizzled, dbuf
  __shared__ alignas(16) char vtl[2][8192];       // V^T tiles [hd][tok], swizzled, dbuf
  __shared__ alignas(16) char pl[8][2048];        // per-wave P [q][tok], swizzled
  __shared__ unsigned yxh[896];                   // packed half2 coords (y lo, x hi)

  for (int j = tid; j < 896; j += 512) {
    unsigned jc = j < NTOK ? (unsigned)j : (NTOK - 1);
    __half hy = __float2half((float)(jc / 29u) * (1.f / 28.f));
    __half hx = __float2half((float)(jc % 29u) * (1.f / 28.f));
    yxh[j] = (unsigned)__half_as_ushort(hy) | ((unsigned)__half_as_ushort(hx) << 16);
  }

  // Q fragments from head-contiguous Qp (this wave's 16-row slice of 128)
  const char* qb = (const char*)(Qp + ((size_t)bh * 896 + qp * 128) * 64);
  short8 qf0 = *(const short8*)(qb + (w * 16 + lc) * 128 + lg * 16);
  short8 qf1 = *(const short8*)(qb + (w * 16 + lc) * 128 + 64 + lg * 16);

  const char* kbase = (const char*)Kp + (size_t)bh * 14 * 8192;
  const char* vbase = (const char*)Vp + (size_t)bh * 14 * 8192;

  // staging: 8 waves cover 8KB each of K and V (1 load per tensor per thread)
  auto stage = [&](int b, int kt) {
    int off = w * 1024;
    __builtin_amdgcn_global_load_lds(
        (const __attribute__((address_space(1))) void*)(kbase + kt * 8192 + off + lane * 16),
        (__attribute__((address_space(3))) void*)(ktl[b] + off), 16, 0, 0);
    __builtin_amdgcn_global_load_lds(
        (const __attribute__((address_space(1))) void*)(vbase + kt * 8192 + off + lane * 16),
        (__attribute__((address_space(3))) void*)(vtl[b] + off), 16, 0, 0);
  };

  f32x4 of[4] = {};
  float mrow[4], psum[4];
  #pragma unroll
  for (int r = 0; r < 4; ++r) { mrow[r] = -3e38f; psum[r] = 0.f; }

  stage(0, 0);
  asm volatile("s_waitcnt vmcnt(0)" ::: "memory");
  __syncthreads();

  // per-row coord weights (row-const lwh*|q|^2 dropped: softmax-invariant)
  float qyw[4], qxw[4];
  #pragma unroll
  for (int r = 0; r < 4; ++r) {
    int iq = qp * 128 + w * 16 + (lg << 2) + r;     // <= 895
    unsigned p = yxh[iq];
    float qy = __half2float(__ushort_as_half((unsigned short)p));
    float qx = __half2float(__ushort_as_half((unsigned short)(p >> 16)));
    qyw[r] = -2.f * lwh * qy;
    qxw[r] = -2.f * lwh * qx;
  }

  for (int kt = 0; kt < 14; ++kt) {
    const int b = kt & 1;
    if (kt < 13) stage(b ^ 1, kt + 1);  // issue next-tile loads early (T14)

    const char* kb = ktl[b];
    const char* vb = vtl[b];
    f32x4 sf[4];
    __builtin_amdgcn_s_setprio(1);
    #pragma unroll
    for (int nt = 0; nt < 4; ++nt) {
      short8 kf0 = *(const short8*)(kb + swz64(nt * 16 + lc, lg << 3));
      short8 kf1 = *(const short8*)(kb + swz64(nt * 16 + lc, 32 + (lg << 3)));
      f32x4 z = {0.f, 0.f, 0.f, 0.f};
      z = __builtin_amdgcn_mfma_f32_16x16x32_bf16(qf0, kf0, z, 0, 0, 0);
      z = __builtin_amdgcn_mfma_f32_16x16x32_bf16(qf1, kf1, z, 0, 0, 0);
      sf[nt] = z;
    }
    __builtin_amdgcn_s_setprio(0);

    const int jb = kt * 64;
    #pragma unroll
    for (int nt = 0; nt < 4; ++nt) {
      int j = jb + nt * 16 + lc;
      unsigned pj = yxh[j];
      float jy = __half2float(__ushort_as_half((unsigned short)pj));
      float jx = __half2float(__ushort_as_half((unsigned short)(pj >> 16)));
      float bc = lwh * (jy * jy + jx * jx);
      #pragma unroll
      for (int r = 0; r < 4; ++r) {
        float val = sf[nt][r] * scale + bc;
        val += qyw[r] * jy;
        val += qxw[r] * jx;
        sf[nt][r] = val;
      }
    }
    if (jb + 64 > NTOK) {               // tail tile only (uniform branch)
      #pragma unroll
      for (int nt = 0; nt < 4; ++nt) {
        if (jb + nt * 16 + lc >= NTOK) {
          sf[nt][0] = -3e38f; sf[nt][1] = -3e38f; sf[nt][2] = -3e38f; sf[nt][3] = -3e38f;
        }
      }
    }

    float lm[4];
    #pragma unroll
    for (int r = 0; r < 4; ++r)
      lm[r] = fmaxf(fmaxf(sf[0][r], sf[1][r]), fmaxf(sf[2][r], sf[3][r]));
    bool trig = (lm[0] > mrow[0] + 12.f) | (lm[1] > mrow[1] + 12.f) |
                (lm[2] > mrow[2] + 12.f) | (lm[3] > mrow[3] + 12.f);
    if (__any(trig)) {
      #pragma unroll
      for (int r = 0; r < 4; ++r) {
        float tm = lm[r];
        #pragma unroll
        for (int m = 1; m < 16; m <<= 1) tm = fmaxf(tm, __shfl_xor(tm, m));
        float mnew = fmaxf(mrow[r], tm);
        float alpha = fexp2(mrow[r] - mnew);
        psum[r] *= alpha;
        of[0][r] *= alpha; of[1][r] *= alpha; of[2][r] *= alpha; of[3][r] *= alpha;
        mrow[r] = mnew;
      }
    }

    // exp2 + per-lane psum + packed bf16 conversion (v_cvt_pk, RNE)
    char* plw = pl[w];
    #pragma unroll
    for (int nt = 0; nt < 4; ++nt) {
      float p0 = fexp2(sf[nt][0] - mrow[0]);
      float p1 = fexp2(sf[nt][1] - mrow[1]);
      float p2 = fexp2(sf[nt][2] - mrow[2]);
      float p3 = fexp2(sf[nt][3] - mrow[3]);
      psum[0] += p0; psum[1] += p1; psum[2] += p2; psum[3] += p3;
      unsigned w01, w23;
      asm("v_cvt_pk_bf16_f32 %0, %1, %2" : "=v"(w01) : "v"(p0), "v"(p1));
      asm("v_cvt_pk_bf16_f32 %0, %1, %2" : "=v"(w23) : "v"(p2), "v"(p3));
      int col = nt * 16 + lc;
      *(u16*)(plw + swz64((lg << 2) + 0, col)) = (u16)w01;
      *(u16*)(plw + swz64((lg << 2) + 1, col)) = (u16)(w01 >> 16);
      *(u16*)(plw + swz64((lg << 2) + 2, col)) = (u16)w23;
      *(u16*)(plw + swz64((lg << 2) + 3, col)) = (u16)(w23 >> 16);
    }
    asm volatile("s_waitcnt lgkmcnt(0)" ::: "memory");
    __builtin_amdgcn_sched_barrier(0);
    short8 pa[2];
    #pragma unroll
    for (int t = 0; t < 2; ++t)
      pa[t] = *(const short8*)(plw + swz64(lc, t * 32 + (lg << 3)));

    __builtin_amdgcn_s_setprio(1);
    #pragma unroll
    for (int n2 = 0; n2 < 4; ++n2) {
      f32x4 accv = of[n2];
      #pragma unroll
      for (int t = 0; t < 2; ++t) {
        short8 vf = *(const short8*)(vb + swz64(n2 * 16 + lc, t * 32 + (lg << 3)));
        accv = __builtin_amdgcn_mfma_f32_16x16x32_bf16(pa[t], vf, accv, 0, 0, 0);
      }
      of[n2] = accv;
    }
    __builtin_amdgcn_s_setprio(0);

    if (kt < 13) {
      // next tile ready (own loads done) + all my LDS reads of buf b sampled
      asm volatile("s_waitcnt vmcnt(0) lgkmcnt(0)" ::: "memory");
      __builtin_amdgcn_sched_barrier(0);
      __builtin_amdgcn_s_barrier();
    }
  }

  // final: per-row sum reduce (16 lanes) + normalized output
  const int bimg = bh / NH_;
  #pragma unroll
  for (int r = 0; r < 4; ++r) {
    float s = psum[r];
    #pragma unroll
    for (int m = 1; m < 16; m <<= 1) s += __shfl_xor(s, m);
    int iq = qp * 128 + w * 16 + (lg << 2) + r;
    if (iq < NTOK) {
      float rl = 1.f / s;
      #pragma unroll
      for (int n2 = 0; n2 < 4; ++n2)
        ob[((size_t)(bimg * NTOK + iq)) * E_ + hh * 64 + n2 * 16 + lc] =
            f2bf(of[n2][r] * rl);
    }
  }
}

extern "C" void kernel_launch(void* const* d_in, const int* in_sizes, int n_in,
                              void* d_out, int out_size, void* d_ws, size_t ws_size,
                              hipStream_t stream) {
  const float* x      = (const float*)d_in[0];
  const float* tok_ng = (const float*)d_in[1];
  const float* tok_nb = (const float*)d_in[2];
  const float* tok_w1 = (const float*)d_in[3];
  const float* tok_b1 = (const float*)d_in[4];
  const float* tok_w2 = (const float*)d_in[5];
  const float* tok_b2 = (const float*)d_in[6];
  const float* ln1_g  = (const float*)d_in[7];
  const float* ln1_b  = (const float*)d_in[8];
  const float* w_qkv  = (const float*)d_in[9];
  const float* temp   = (const float*)d_in[10];
  const float* loc_w  = (const float*)d_in[11];
  const float* w_proj = (const float*)d_in[12];
  const float* b_proj = (const float*)d_in[13];
  const float* ls1    = (const float*)d_in[14];
  const float* ln2_g  = (const float*)d_in[15];
  const float* ln2_b  = (const float*)d_in[16];
  const float* ff_w1  = (const float*)d_in[17];
  const float* ff_b1  = (const float*)d_in[18];
  const float* ff_w2  = (const float*)d_in[19];
  const float* ff_b2  = (const float*)d_in[20];
  const float* ls2    = (const float*)d_in[21];
  float* out = (float*)d_out;

  char* ws = (char*)d_ws;
  size_t off = 0;
  auto alloc = [&](size_t bytes) -> void* {
    void* p = ws + off; off += (bytes + 255) & ~(size_t)255; return p;
  };
  // weights (persistent per launch)
  u16* w1T   = (u16*)alloc(768UL * 3840 * 2);
  u16* w2T   = (u16*)alloc(384UL * 768 * 2);
  u16* qkvT  = (u16*)alloc(8UL * 1152 * 384 * 2);
  u16* projT = (u16*)alloc(8UL * 384 * 384 * 2);
  u16* f1T   = (u16*)alloc(8UL * 1536 * 384 * 2);
  u16* f2T   = (u16*)alloc(8UL * 384 * 1536 * 2);
  // persistent activation
  float* h   = (float*)alloc((size_t)MP * 384 * 4);
  // regB: h1 (embed) OR { ypad/yff | ob } (blocks)
  char* regB = (char*)alloc(22500000);
  u16* h1   = (u16*)regB;                               // [MP][768] bf16 (embed)
  u16* ypad = (u16*)regB;                               // [MQ][384] = 11.01MB
  u16* yff  = (u16*)regB;                               // [MP][384] (ln2 out)
  u16* ob   = (u16*)(regB + 11010048);                  // [MP][384] = 10.42MB
  // regA: Xlnc (embed) OR Qp/Kp/Vp (attn) OR f1b (ff)
  char* regA = (char*)alloc((size_t)MP * 1536 * 2);
  u16* Xlnc = (u16*)regA;
  u16* Qp   = (u16*)regA;                               // 96*896*64*2  = 11.0MB
  u16* Kp   = (u16*)(regA + 11010048);                  // 96*14*8192   = 11.0MB
  u16* Vp   = (u16*)(regA + 22020096);                  // 11.0MB (33MB <= 41.7MB)
  u16* f1b  = (u16*)regA;
  (void)in_sizes; (void)n_in; (void)out_size;

  if (off > ws_size) return;  // diagnostic: leaves d_out untouched -> absmax ~2.5

  // weight transposes (fp32 [K][N] -> bf16 [N][K])
  transpose_conv<<<dim3(24, 120, 1), 256, 0, stream>>>(tok_w1, w1T, 3840, 768);
  transpose_conv<<<dim3(12, 24, 1), 256, 0, stream>>>(tok_w2, w2T, 768, 384);
  transpose_conv<<<dim3(36, 12, 8), 256, 0, stream>>>(w_qkv, qkvT, 384, 1152);
  transpose_conv<<<dim3(12, 12, 8), 256, 0, stream>>>(w_proj, projT, 384, 384);
  transpose_conv<<<dim3(48, 12, 8), 256, 0, stream>>>(ff_w1, f1T, 384, 1536);
  transpose_conv<<<dim3(12, 48, 8), 256, 0, stream>>>(ff_w2, f2T, 1536, 384);

  // patch embed + LN(3840) + first GEMM, chunked through Xlnc
  for (int m = 0; m < MP; m += CM) {
    int rows = MP - m; if (rows > CM) rows = CM;
    patch_ln<<<rows, 256, 0, stream>>>(x, tok_ng, tok_nb, Xlnc, m);
    gemm_bt<1, 128, 64><<<dim3(6, rows / 128), 256, 0, stream>>>(Xlnc, w1T, 768, 3840,
        tok_b1, nullptr, nullptr, h1 + (size_t)m * 768, nullptr);
  }
  gemm_bt<2, 64, 32><<<dim3(3, MP / 64), 256, 0, stream>>>(h1, w2T, 384, 768, tok_b2,
      nullptr, nullptr, nullptr, h);

  for (int d = 0; d < 8; ++d) {
    ln384p<<<MQ / 4, 256, 0, stream>>>(h, ln1_g + d * E_, ln1_b + d * E_, ypad);
    gemm_qkv<<<dim3(9, 112), 256, 0, stream>>>(ypad, qkvT + (size_t)d * 1152 * 384, Qp, Kp, Vp);
    attn_sp<<<672, 512, 0, stream>>>(Qp, Kp, Vp, temp + d * NH_, loc_w + d * NH_, ob);
    gemm_bt<3, 64, 32><<<dim3(3, MP / 64), 256, 0, stream>>>(ob, projT + (size_t)d * 384 * 384,
        384, 384, b_proj + d * E_, ls1 + d * E_, h, nullptr, nullptr);
    ln384<<<MP / 4, 256, 0, stream>>>(h, ln2_g + d * E_, ln2_b + d * E_, yff);
    gemm_bt<1, 128, 32><<<dim3(12, MP / 128), 256, 0, stream>>>(yff, f1T + (size_t)d * 1536 * 384,
        1536, 384, ff_b1 + d * 1536, nullptr, nullptr, f1b, nullptr);
    if (d < 7)
      gemm_bt<3, 64, 32><<<dim3(3, MP / 64), 256, 0, stream>>>(f1b, f2T + (size_t)d * 384 * 1536,
          384, 1536, ff_b2 + d * E_, ls2 + d * E_, h, nullptr, nullptr);
    else
      gemm_bt<4, 64, 32><<<dim3(3, MP / 64), 256, 0, stream>>>(f1b, f2T + (size_t)d * 384 * 1536,
          384, 1536, ff_b2 + d * E_, ls2 + d * E_, h, nullptr, out);
  }
}

// Round 21
// 1693.078 us; speedup vs baseline: 1.0515x; 1.0515x over previous
//
#include <hip/hip_runtime.h>
#include <math.h>

typedef __attribute__((ext_vector_type(8))) short short8;
typedef __attribute__((ext_vector_type(4))) float f32x4;
typedef unsigned short u16;

#define NTOK 841
#define GRID_H 29
#define E_ 384
#define NH_ 6
#define MROWS 13456
#define MP 13568
#define MQ 14336
#define CM 5120

__device__ __forceinline__ u16 f2bf(float f) {
  union { float f; unsigned int u; } c; c.f = f;
  unsigned int u = c.u;
  return (u16)((u + 0x7fffu + ((u >> 16) & 1u)) >> 16);
}

__device__ __forceinline__ float bf2f(u16 b) {
  union { unsigned int u; float f; } c; c.u = ((unsigned int)b) << 16; return c.f;
}

__device__ __forceinline__ float gelu_exact(float v) {
  return 0.5f * v * (1.f + erff(v * 0.70710678118654752440f));
}

__device__ __forceinline__ float fexp2(float x) {
  float r; asm("v_exp_f32 %0, %1" : "=v"(r) : "v"(x)); return r;
}

// byte offset in a [rows][64]-bf16 tile (128B/row), 16B-chunk XOR swizzle
__device__ __forceinline__ int swz64(int row, int col) {
  return row * 128 + ((((col >> 3) ^ (row & 7)) << 4) | ((col & 7) << 1));
}

// ---------------- transpose + fp32->bf16 convert: in [K][N] -> out [N][K] ----
__global__ __launch_bounds__(256) void transpose_conv(const float* __restrict__ in,
    u16* __restrict__ out, int K, int N) {
  __shared__ float tile[32][33];
  size_t zo = (size_t)blockIdx.z * K * N;
  const float* inp = in + zo;
  u16* outp = out + zo;
  int n0 = blockIdx.x * 32, k0 = blockIdx.y * 32;
  int tx = threadIdx.x & 31, ty = threadIdx.x >> 5;
  #pragma unroll
  for (int r = ty; r < 32; r += 8) tile[r][tx] = inp[(size_t)(k0 + r) * N + n0 + tx];
  __syncthreads();
  #pragma unroll
  for (int r = ty; r < 32; r += 8) outp[(size_t)(n0 + r) * K + k0 + tx] = f2bf(tile[tx][r]);
}

// ---------------- fused 5-shift patchify + LayerNorm(3840) -> bf16 ----------
__global__ __launch_bounds__(256) void patch_ln(const float* __restrict__ x,
    const float* __restrict__ g, const float* __restrict__ bsh, u16* __restrict__ out,
    int t0) {
  int t = t0 + blockIdx.x;
  int tid = threadIdx.x;
  u16* orow = out + (size_t)blockIdx.x * 3840;
  if (t >= MROWS) {
    #pragma unroll
    for (int j = 0; j < 15; ++j) orow[tid + j * 256] = 0;  // bf16 zero
    return;
  }
  int bimg = t / NTOK, n = t % NTOK;
  int gy = n / GRID_H, gx = n % GRID_H;
  float vals[15];
  float s1 = 0.f, s2 = 0.f;
  #pragma unroll
  for (int j = 0; j < 15; ++j) {
    int cout = tid + j * 256;
    int s = cout / 768, rem = cout % 768;
    int c = rem / 256, rem2 = rem % 256;
    int py = rem2 / 16, px = rem2 % 16;
    int dy = (s == 1 ? 8 : 0) - (s == 2 ? 8 : 0);
    int dx = (s == 3 ? 8 : 0) - (s == 4 ? 8 : 0);
    int Y = gy * 16 + py - dy;
    int X = gx * 16 + px - dx;
    float v = 0.f;
    if (Y >= 0 && Y < 464 && X >= 0 && X < 464)
      v = x[(((size_t)bimg * 3 + c) * 464 + Y) * 464 + X];
    vals[j] = v;
    s1 += v; s2 += v * v;
  }
  #pragma unroll
  for (int m = 1; m < 64; m <<= 1) { s1 += __shfl_xor(s1, m); s2 += __shfl_xor(s2, m); }
  __shared__ float ws1[4], ws2[4];
  int wid = tid >> 6;
  if ((tid & 63) == 0) { ws1[wid] = s1; ws2[wid] = s2; }
  __syncthreads();
  s1 = ws1[0] + ws1[1] + ws1[2] + ws1[3];
  s2 = ws2[0] + ws2[1] + ws2[2] + ws2[3];
  float mean = s1 * (1.f / 3840.f);
  float var = s2 * (1.f / 3840.f) - mean * mean;
  float rs = rsqrtf(var + 1e-5f);
  #pragma unroll
  for (int j = 0; j < 15; ++j) {
    int cout = tid + j * 256;
    orow[cout] = f2bf((vals[j] - mean) * rs * g[cout] + bsh[cout]);
  }
}

// ---------------- LayerNorm(384) fp32 -> bf16 (packed MP rows) ---------------
__global__ __launch_bounds__(256) void ln384(const float* __restrict__ h,
    const float* __restrict__ g, const float* __restrict__ bsh, u16* __restrict__ y) {
  int row = blockIdx.x * 4 + (threadIdx.x >> 6);
  int lane = threadIdx.x & 63;
  const float* hr = h + (size_t)row * E_;
  float v[6];
  float s1 = 0.f;
  #pragma unroll
  for (int j = 0; j < 6; ++j) { v[j] = hr[lane + j * 64]; s1 += v[j]; }
  #pragma unroll
  for (int m = 1; m < 64; m <<= 1) s1 += __shfl_xor(s1, m);
  float mean = s1 * (1.f / 384.f);
  float s2 = 0.f;
  #pragma unroll
  for (int j = 0; j < 6; ++j) { float d = v[j] - mean; s2 += d * d; }
  #pragma unroll
  for (int m = 1; m < 64; m <<= 1) s2 += __shfl_xor(s2, m);
  float rs = rsqrtf(s2 * (1.f / 384.f) + 1e-5f);
  u16* yr = y + (size_t)row * E_;
  #pragma unroll
  for (int j = 0; j < 6; ++j) {
    int c = lane + j * 64;
    yr[c] = f2bf((v[j] - mean) * rs * g[c] + bsh[c]);
  }
}

// ---------------- LayerNorm(384) -> 896-padded bf16 (zeros on pad rows) ------
__global__ __launch_bounds__(256) void ln384p(const float* __restrict__ h,
    const float* __restrict__ g, const float* __restrict__ bsh, u16* __restrict__ yp) {
  int rowp = blockIdx.x * 4 + (threadIdx.x >> 6);
  int lane = threadIdx.x & 63;
  int bg = rowp / 896, tk = rowp - bg * 896;
  u16* yr = yp + (size_t)rowp * E_;
  if (tk >= NTOK) {
    #pragma unroll
    for (int j = 0; j < 6; ++j) yr[lane + j * 64] = 0;
    return;
  }
  const float* hr = h + (size_t)(bg * NTOK + tk) * E_;
  float v[6];
  float s1 = 0.f;
  #pragma unroll
  for (int j = 0; j < 6; ++j) { v[j] = hr[lane + j * 64]; s1 += v[j]; }
  #pragma unroll
  for (int m = 1; m < 64; m <<= 1) s1 += __shfl_xor(s1, m);
  float mean = s1 * (1.f / 384.f);
  float s2 = 0.f;
  #pragma unroll
  for (int j = 0; j < 6; ++j) { float d = v[j] - mean; s2 += d * d; }
  #pragma unroll
  for (int m = 1; m < 64; m <<= 1) s2 += __shfl_xor(s2, m);
  float rs = rsqrtf(s2 * (1.f / 384.f) + 1e-5f);
  #pragma unroll
  for (int j = 0; j < 6; ++j) {
    int c = lane + j * 64;
    yr[c] = f2bf((v[j] - mean) * rs * g[c] + bsh[c]);
  }
}

// ---------------- bf16 MFMA GEMM, min-2-phase pipelined (T3+T4) --------------
// EPI: 1 = bf16 gelu(acc+bias), LDS-staged coalesced out; 2 = f32 acc+bias;
//      3 = resid[m][n] += lscale[n]*(acc+bias[n]);
//      4 = outf[m][n] = resid[m][n] + lscale[n]*(acc+bias[n]) (final, m<MROWS)
// BK: 64 (8-chunk swizzle) or 32 (4-chunk swizzle, halves LDS for occupancy)
template<int EPI, int TM, int BK>
__global__ __launch_bounds__(256) void gemm_bt(
    const u16* __restrict__ A, const u16* __restrict__ BT,
    int N, int K,
    const float* __restrict__ bias, const float* __restrict__ lscale,
    float* __restrict__ resid, u16* __restrict__ outb, float* __restrict__ outf) {
  constexpr int MI = TM / 32;
  constexpr int BUF = (TM + 128) * BK;              // shorts per buffer
  constexpr int SM1 = 2 * BUF * 2;
  constexpr int SM2 = (EPI == 1) ? TM * 136 * 2 : 0;
  constexpr int SMEM = SM1 > SM2 ? SM1 : SM2;
  __shared__ alignas(16) char smem[SMEM];
  short* As = (short*)smem;
  // bijective XCD swizzle (m204)
  const int gx = gridDim.x;
  const int nwg = gx * gridDim.y;
  int L = blockIdx.x + blockIdx.y * gx;
  int q8 = nwg >> 3, r8 = nwg & 7, xcd = L & 7, pos = L >> 3;
  int L2 = (xcd < r8 ? xcd * (q8 + 1) : r8 * (q8 + 1) + (xcd - r8) * q8) + pos;
  const int m0 = (L2 / gx) * TM, n0 = (L2 % gx) * 128;
  const int tid = threadIdx.x;
  const int lane = tid & 63, wid = tid >> 6;
  const int wm = wid >> 1, wn = wid & 1;
  f32x4 acc[MI][4] = {};
  const int nkt = K / BK;

  auto stage = [&](int b, int kt) {
    short* Ab = As + b * BUF;
    short* Bb = Ab + TM * BK;
    const int k0 = kt * BK;
    if constexpr (BK == 64) {
      const int rowl = lane >> 3;
      const int colc = (((lane & 7) ^ (rowl & 7)) << 3);
      #pragma unroll
      for (int i = 0; i < TM / 32; ++i) {
        int chunk = i * 4 + wid;
        const u16* ga = A + (size_t)(m0 + chunk * 8 + rowl) * K + k0 + colc;
        __builtin_amdgcn_global_load_lds((const __attribute__((address_space(1))) void*)ga,
            (__attribute__((address_space(3))) void*)(Ab + (chunk << 9)), 16, 0, 0);
      }
      #pragma unroll
      for (int i = 0; i < 4; ++i) {
        int chunk = i * 4 + wid;
        const u16* gb = BT + (size_t)(n0 + chunk * 8 + rowl) * K + k0 + colc;
        __builtin_amdgcn_global_load_lds((const __attribute__((address_space(1))) void*)gb,
            (__attribute__((address_space(3))) void*)(Bb + (chunk << 9)), 16, 0, 0);
      }
    } else {
      const int rowl = lane >> 2;                 // 16 rows per wave-slab
      const int colc = (((lane & 3) ^ (rowl & 3)) << 3);
      #pragma unroll
      for (int i = 0; i < TM / 64; ++i) {
        int rbase = i * 64 + wid * 16;
        const u16* ga = A + (size_t)(m0 + rbase + rowl) * K + k0 + colc;
        __builtin_amdgcn_global_load_lds((const __attribute__((address_space(1))) void*)ga,
            (__attribute__((address_space(3))) void*)(Ab + rbase * 32), 16, 0, 0);
      }
      #pragma unroll
      for (int i = 0; i < 2; ++i) {
        int rbase = i * 64 + wid * 16;
        const u16* gb = BT + (size_t)(n0 + rbase + rowl) * K + k0 + colc;
        __builtin_amdgcn_global_load_lds((const __attribute__((address_space(1))) void*)gb,
            (__attribute__((address_space(3))) void*)(Bb + rbase * 32), 16, 0, 0);
      }
    }
  };

  const int lg = lane >> 4;
  stage(0, 0);
  for (int kt = 0; kt < nkt; ++kt) {
    const int cur = kt & 1;
    if (kt + 1 < nkt) {
      stage(cur ^ 1, kt + 1);
      // wait own current-tile loads (allow next tile's NL in flight)
      if constexpr (BK == 64) {
        if constexpr (TM == 128) asm volatile("s_waitcnt vmcnt(8)" ::: "memory");
        else                     asm volatile("s_waitcnt vmcnt(6)" ::: "memory");
      } else {
        if constexpr (TM == 128) asm volatile("s_waitcnt vmcnt(4)" ::: "memory");
        else                     asm volatile("s_waitcnt vmcnt(3)" ::: "memory");
      }
    } else {
      asm volatile("s_waitcnt vmcnt(0)" ::: "memory");
    }
    __builtin_amdgcn_s_barrier();       // all waves' current tile complete
    __builtin_amdgcn_sched_barrier(0);
    short* Ab = As + cur * BUF;
    short* Bb = Ab + TM * BK;
    #pragma unroll
    for (int kk = 0; kk < BK / 32; ++kk) {
      short8 a[MI], bfr[4];
      #pragma unroll
      for (int mi = 0; mi < MI; ++mi) {
        int ra = wm * (TM / 2) + mi * 16 + (lane & 15);
        int off = (BK == 64) ? ((((kk << 2) | lg) ^ (ra & 7)) << 3)
                             : ((lg ^ (ra & 3)) << 3);
        a[mi] = *(const short8*)(Ab + ra * BK + off);
      }
      #pragma unroll
      for (int nj = 0; nj < 4; ++nj) {
        int rb = wn * 64 + nj * 16 + (lane & 15);
        int off = (BK == 64) ? ((((kk << 2) | lg) ^ (rb & 7)) << 3)
                             : ((lg ^ (rb & 3)) << 3);
        bfr[nj] = *(const short8*)(Bb + rb * BK + off);
      }
      #pragma unroll
      for (int mi = 0; mi < MI; ++mi)
        #pragma unroll
        for (int nj = 0; nj < 4; ++nj)
          acc[mi][nj] = __builtin_amdgcn_mfma_f32_16x16x32_bf16(a[mi], bfr[nj], acc[mi][nj], 0, 0, 0);
    }
    __builtin_amdgcn_s_barrier();       // reads of 'cur' done before its overwrite
  }
  const int rrow = (lane >> 4) << 2;
  const int ccol = lane & 15;
  if (EPI == 1) {
    // stage C in LDS, write coalesced full rows
    u16* Cs = (u16*)smem;
    __syncthreads();
    #pragma unroll
    for (int mi = 0; mi < MI; ++mi)
      #pragma unroll
      for (int nj = 0; nj < 4; ++nj) {
        int cc = wn * 64 + nj * 16 + ccol;
        float bi = bias[n0 + cc];
        #pragma unroll
        for (int r = 0; r < 4; ++r) {
          int cr = wm * (TM / 2) + mi * 16 + rrow + r;
          Cs[cr * 136 + cc] = f2bf(gelu_exact(acc[mi][nj][r] + bi));
        }
      }
    __syncthreads();
    #pragma unroll
    for (int it = 0; it < TM / 16; ++it) {
      int idx = it * 256 + tid;
      int orow = idx >> 4, c = idx & 15;
      short8 v = *(const short8*)(Cs + orow * 136 + c * 8);
      *(short8*)(outb + (size_t)(m0 + orow) * N + n0 + c * 8) = v;
    }
    return;
  }
  #pragma unroll
  for (int mi = 0; mi < MI; ++mi)
    #pragma unroll
    for (int nj = 0; nj < 4; ++nj) {
      int gn = n0 + wn * 64 + nj * 16 + ccol;
      #pragma unroll
      for (int r = 0; r < 4; ++r) {
        int gm = m0 + wm * (TM / 2) + mi * 16 + rrow + r;
        float v = acc[mi][nj][r];
        if (EPI == 2) {
          outf[(size_t)gm * N + gn] = v + bias[gn];
        } else if (EPI == 3) {
          float* p = resid + (size_t)gm * N + gn;
          *p = *p + lscale[gn] * (v + bias[gn]);
        } else {
          if (gm < MROWS)
            outf[(size_t)gm * N + gn] =
                resid[(size_t)gm * N + gn] + lscale[gn] * (v + bias[gn]);
        }
      }
    }
}

// ---------------- qkv GEMM over padded-896 rows, pipelined, swizzled out -----
__global__ __launch_bounds__(256) void gemm_qkv(
    const u16* __restrict__ A, const u16* __restrict__ BT,
    u16* __restrict__ Qp, u16* __restrict__ Kp, u16* __restrict__ Vp) {
  const int K = 384;
  constexpr int BUF = 256 * 64;
  __shared__ alignas(16) char smem[2 * BUF * 2];   // 64KB dbuf; Cs aliases
  short* As = (short*)smem;
  // XCD swizzle over 1008 blocks (1008 = 8*126)
  int L = blockIdx.x + blockIdx.y * 9;
  int L2 = (L & 7) * 126 + (L >> 3);
  const int m0 = (L2 / 9) * 128, n0 = (L2 % 9) * 128;
  const int tid = threadIdx.x;
  const int lane = tid & 63, wid = tid >> 6;
  const int wm = wid >> 1, wn = wid & 1;
  const int rowl = lane >> 3;
  const int colc = (((lane & 7) ^ (rowl & 7)) << 3);
  f32x4 acc[4][4] = {};

  auto stage = [&](int b, int kt) {
    short* Ab = As + b * BUF;
    short* Bb = Ab + 128 * 64;
    const int k0 = kt * 64;
    #pragma unroll
    for (int i = 0; i < 4; ++i) {
      int chunk = i * 4 + wid;
      const u16* ga = A + (size_t)(m0 + chunk * 8 + rowl) * K + k0 + colc;
      __builtin_amdgcn_global_load_lds((const __attribute__((address_space(1))) void*)ga,
          (__attribute__((address_space(3))) void*)(Ab + (chunk << 9)), 16, 0, 0);
      const u16* gb = BT + (size_t)(n0 + chunk * 8 + rowl) * K + k0 + colc;
      __builtin_amdgcn_global_load_lds((const __attribute__((address_space(1))) void*)gb,
          (__attribute__((address_space(3))) void*)(Bb + (chunk << 9)), 16, 0, 0);
    }
  };

  stage(0, 0);
  for (int kt = 0; kt < 6; ++kt) {
    const int cur = kt & 1;
    if (kt + 1 < 6) {
      stage(cur ^ 1, kt + 1);
      asm volatile("s_waitcnt vmcnt(8)" ::: "memory");
    } else {
      asm volatile("s_waitcnt vmcnt(0)" ::: "memory");
    }
    __builtin_amdgcn_s_barrier();
    __builtin_amdgcn_sched_barrier(0);
    short* Ab = As + cur * BUF;
    short* Bb = Ab + 128 * 64;
    #pragma unroll
    for (int kk = 0; kk < 2; ++kk) {
      short8 a[4], bfr[4];
      #pragma unroll
      for (int mi = 0; mi < 4; ++mi) {
        int ra = wm * 64 + mi * 16 + (lane & 15);
        a[mi] = *(const short8*)(Ab + ra * 64 + ((((kk << 2) | (lane >> 4)) ^ (ra & 7)) << 3));
      }
      #pragma unroll
      for (int nj = 0; nj < 4; ++nj) {
        int rb = wn * 64 + nj * 16 + (lane & 15);
        bfr[nj] = *(const short8*)(Bb + rb * 64 + ((((kk << 2) | (lane >> 4)) ^ (rb & 7)) << 3));
      }
      #pragma unroll
      for (int mi = 0; mi < 4; ++mi)
        #pragma unroll
        for (int nj = 0; nj < 4; ++nj)
          acc[mi][nj] = __builtin_amdgcn_mfma_f32_16x16x32_bf16(a[mi], bfr[nj], acc[mi][nj], 0, 0, 0);
    }
    __builtin_amdgcn_s_barrier();
  }
  // epilogue: stage in LDS ([tok][col] for Q/K, transposed [col][tok] for V)
  const int seg = n0 / 384;                 // 0=Q 1=K 2=V (block-uniform)
  const int h0 = (n0 - seg * 384) >> 6;     // head pair base: 0,2,4
  const int bg = m0 / 896;
  const int tk0 = m0 - bg * 896;            // 0..768, 64-tile aligned
  const int rrow = (lane >> 4) << 2;
  const int ccol = lane & 15;
  u16* Cs = (u16*)smem;
  __syncthreads();
  #pragma unroll
  for (int mi = 0; mi < 4; ++mi)
    #pragma unroll
    for (int nj = 0; nj < 4; ++nj) {
      int cc = wn * 64 + nj * 16 + ccol;
      #pragma unroll
      for (int r = 0; r < 4; ++r) {
        int cr = wm * 64 + mi * 16 + rrow + r;
        u16 bv = f2bf(acc[mi][nj][r]);
        if (seg == 2) Cs[cc * 136 + cr] = bv;
        else          Cs[cr * 136 + cc] = bv;
      }
    }
  __syncthreads();
  // write out 256 rows x 128B, full-line short8 stores
  #pragma unroll
  for (int i = 0; i < 8; ++i) {
    int idx = i * 256 + tid;
    int c = idx & 7;                 // 16B chunk within 128B row
    int orow = idx >> 3;             // 0..255
    int hs = orow >> 7;              // head select
    int rl = orow & 127;
    size_t bh = (size_t)(bg * 6 + h0 + hs);
    if (seg == 2) {
      int tile_l = rl >> 6, hd = rl & 63;
      short8 v = *(const short8*)(Cs + (hs * 64 + hd) * 136 + tile_l * 64 + c * 8);
      int tile = (tk0 >> 6) + tile_l;
      *(short8*)(Vp + bh * 57344 + tile * 4096 + hd * 64 + ((c ^ (hd & 7)) << 3)) = v;
    } else {
      short8 v = *(const short8*)(Cs + rl * 136 + hs * 64 + c * 8);
      if (seg == 0) {
        *(short8*)(Qp + (bh * 896 + tk0 + rl) * 64 + c * 8) = v;
      } else {
        int tok = tk0 + rl;
        *(short8*)(Kp + bh * 57344 + (tok >> 6) * 4096 + (tok & 63) * 64 + ((c ^ (tok & 7)) << 3)) = v;
      }
    }
  }
}

// ---------------- single-pass flash attention, 8 waves / 128 q-rows ----------
__global__ __launch_bounds__(512) void attn_sp(const u16* __restrict__ Qp,
    const u16* __restrict__ Kp, const u16* __restrict__ Vp,
    const float* __restrict__ temp_d, const float* __restrict__ locw_d,
    u16* __restrict__ ob) {
  // 1D grid = hardware dispatch order; bijective XCD swizzle: 672 = 8*84.
  int Lw = blockIdx.x;
  int L2 = (Lw & 7) * 84 + (Lw >> 3);
  const int bh = L2 / 7, qp = L2 % 7;       // qp = 128-row q-block
  const int hh = bh % NH_;
  const int tid = threadIdx.x, lane = tid & 63, w = tid >> 6;   // w in [0,8)
  const int lg = lane >> 4, lc = lane & 15;
  const float LOG2E = 1.44269504088896f;
  const float scale = __expf(temp_d[hh]) * LOG2E;   // exp2-domain
  const float lwh = locw_d[hh] * LOG2E * -0.5f;

  __shared__ alignas(16) char ktl[2][8192];       // K tiles [tok][hd], swizzled, dbuf
  __shared__ alignas(16) char vtl[2][8192];       // V^T tiles [hd][tok], swizzled, dbuf
  __shared__ alignas(16) char pl[8][2048];        // per-wave P [q][tok], swizzled
  __shared__ float yx2[896 * 2];                  // token coords (y,x)

  for (int j = tid; j < 896; j += 512) {
    unsigned jc = j < NTOK ? (unsigned)j : (NTOK - 1);
    yx2[j * 2]     = (float)(jc / 29u) * (1.f / 28.f);
    yx2[j * 2 + 1] = (float)(jc % 29u) * (1.f / 28.f);
  }

  // Q fragments from head-contiguous Qp (this wave's 16-row slice of 128)
  const char* qb = (const char*)(Qp + ((size_t)bh * 896 + qp * 128) * 64);
  short8 qf0 = *(const short8*)(qb + (w * 16 + lc) * 128 + lg * 16);
  short8 qf1 = *(const short8*)(qb + (w * 16 + lc) * 128 + 64 + lg * 16);

  const char* kbase = (const char*)Kp + (size_t)bh * 14 * 8192;
  const char* vbase = (const char*)Vp + (size_t)bh * 14 * 8192;

  // staging: 8 waves cover 8KB each of K and V (1 load per tensor per thread)
  auto stage = [&](int b, int kt) {
    int off = w * 1024;
    __builtin_amdgcn_global_load_lds(
        (const __attribute__((address_space(1))) void*)(kbase + kt * 8192 + off + lane * 16),
        (__attribute__((address_space(3))) void*)(ktl[b] + off), 16, 0, 0);
    __builtin_amdgcn_global_load_lds(
        (const __attribute__((address_space(1))) void*)(vbase + kt * 8192 + off + lane * 16),
        (__attribute__((address_space(3))) void*)(vtl[b] + off), 16, 0, 0);
  };

  f32x4 of[4] = {};
  float mrow[4], psum[4];
  #pragma unroll
  for (int r = 0; r < 4; ++r) { mrow[r] = -3e38f; psum[r] = 0.f; }

  stage(0, 0);
  asm volatile("s_waitcnt vmcnt(0)" ::: "memory");
  __syncthreads();

  // per-row coord weights (row-const lwh*|q|^2 dropped: softmax-invariant)
  float qyw[4], qxw[4];
  #pragma unroll
  for (int r = 0; r < 4; ++r) {
    int iq = qp * 128 + w * 16 + (lg << 2) + r;     // <= 895
    qyw[r] = -2.f * lwh * yx2[iq * 2];
    qxw[r] = -2.f * lwh * yx2[iq * 2 + 1];
  }

  for (int kt = 0; kt < 14; ++kt) {
    const int b = kt & 1;
    if (kt < 13) stage(b ^ 1, kt + 1);  // issue next-tile loads early (T14)

    const char* kb = ktl[b];
    const char* vb = vtl[b];
    f32x4 sf[4];
    __builtin_amdgcn_s_setprio(1);
    #pragma unroll
    for (int nt = 0; nt < 4; ++nt) {
      short8 kf0 = *(const short8*)(kb + swz64(nt * 16 + lc, lg << 3));
      short8 kf1 = *(const short8*)(kb + swz64(nt * 16 + lc, 32 + (lg << 3)));
      f32x4 z = {0.f, 0.f, 0.f, 0.f};
      z = __builtin_amdgcn_mfma_f32_16x16x32_bf16(qf0, kf0, z, 0, 0, 0);
      z = __builtin_amdgcn_mfma_f32_16x16x32_bf16(qf1, kf1, z, 0, 0, 0);
      sf[nt] = z;
    }
    __builtin_amdgcn_s_setprio(0);

    const int jb = kt * 64;
    #pragma unroll
    for (int nt = 0; nt < 4; ++nt) {
      int j = jb + nt * 16 + lc;
      float jy = yx2[j * 2], jx = yx2[j * 2 + 1];
      float bc = lwh * (jy * jy + jx * jx);
      #pragma unroll
      for (int r = 0; r < 4; ++r) {
        float val = sf[nt][r] * scale + bc;
        val += qyw[r] * jy;
        val += qxw[r] * jx;
        sf[nt][r] = val;
      }
    }
    if (jb + 64 > NTOK) {               // tail tile only (uniform branch)
      #pragma unroll
      for (int nt = 0; nt < 4; ++nt) {
        if (jb + nt * 16 + lc >= NTOK) {
          sf[nt][0] = -3e38f; sf[nt][1] = -3e38f; sf[nt][2] = -3e38f; sf[nt][3] = -3e38f;
        }
      }
    }

    float lm[4];
    #pragma unroll
    for (int r = 0; r < 4; ++r)
      lm[r] = fmaxf(fmaxf(sf[0][r], sf[1][r]), fmaxf(sf[2][r], sf[3][r]));
    bool trig = (lm[0] > mrow[0] + 12.f) | (lm[1] > mrow[1] + 12.f) |
                (lm[2] > mrow[2] + 12.f) | (lm[3] > mrow[3] + 12.f);
    if (__any(trig)) {
      #pragma unroll
      for (int r = 0; r < 4; ++r) {
        float tm = lm[r];
        #pragma unroll
        for (int m = 1; m < 16; m <<= 1) tm = fmaxf(tm, __shfl_xor(tm, m));
        float mnew = fmaxf(mrow[r], tm);
        float alpha = fexp2(mrow[r] - mnew);
        psum[r] *= alpha;
        of[0][r] *= alpha; of[1][r] *= alpha; of[2][r] *= alpha; of[3][r] *= alpha;
        mrow[r] = mnew;
      }
    }

    // exp2 + per-lane psum + packed bf16 conversion (v_cvt_pk, RNE)
    char* plw = pl[w];
    #pragma unroll
    for (int nt = 0; nt < 4; ++nt) {
      float p0 = fexp2(sf[nt][0] - mrow[0]);
      float p1 = fexp2(sf[nt][1] - mrow[1]);
      float p2 = fexp2(sf[nt][2] - mrow[2]);
      float p3 = fexp2(sf[nt][3] - mrow[3]);
      psum[0] += p0; psum[1] += p1; psum[2] += p2; psum[3] += p3;
      unsigned w01, w23;
      asm("v_cvt_pk_bf16_f32 %0, %1, %2" : "=v"(w01) : "v"(p0), "v"(p1));
      asm("v_cvt_pk_bf16_f32 %0, %1, %2" : "=v"(w23) : "v"(p2), "v"(p3));
      int col = nt * 16 + lc;
      *(u16*)(plw + swz64((lg << 2) + 0, col)) = (u16)w01;
      *(u16*)(plw + swz64((lg << 2) + 1, col)) = (u16)(w01 >> 16);
      *(u16*)(plw + swz64((lg << 2) + 2, col)) = (u16)w23;
      *(u16*)(plw + swz64((lg << 2) + 3, col)) = (u16)(w23 >> 16);
    }
    asm volatile("s_waitcnt lgkmcnt(0)" ::: "memory");
    __builtin_amdgcn_sched_barrier(0);
    short8 pa[2];
    #pragma unroll
    for (int t = 0; t < 2; ++t)
      pa[t] = *(const short8*)(plw + swz64(lc, t * 32 + (lg << 3)));

    __builtin_amdgcn_s_setprio(1);
    #pragma unroll
    for (int n2 = 0; n2 < 4; ++n2) {
      f32x4 accv = of[n2];
      #pragma unroll
      for (int t = 0; t < 2; ++t) {
        short8 vf = *(const short8*)(vb + swz64(n2 * 16 + lc, t * 32 + (lg << 3)));
        accv = __builtin_amdgcn_mfma_f32_16x16x32_bf16(pa[t], vf, accv, 0, 0, 0);
      }
      of[n2] = accv;
    }
    __builtin_amdgcn_s_setprio(0);

    if (kt < 13) {
      // next tile ready (own loads done) + all my LDS reads of buf b sampled
      asm volatile("s_waitcnt vmcnt(0) lgkmcnt(0)" ::: "memory");
      __builtin_amdgcn_sched_barrier(0);
      __builtin_amdgcn_s_barrier();
    }
  }

  // final: per-row sum reduce (16 lanes) + normalized output
  const int bimg = bh / NH_;
  #pragma unroll
  for (int r = 0; r < 4; ++r) {
    float s = psum[r];
    #pragma unroll
    for (int m = 1; m < 16; m <<= 1) s += __shfl_xor(s, m);
    int iq = qp * 128 + w * 16 + (lg << 2) + r;
    if (iq < NTOK) {
      float rl = 1.f / s;
      #pragma unroll
      for (int n2 = 0; n2 < 4; ++n2)
        ob[((size_t)(bimg * NTOK + iq)) * E_ + hh * 64 + n2 * 16 + lc] =
            f2bf(of[n2][r] * rl);
    }
  }
}

extern "C" void kernel_launch(void* const* d_in, const int* in_sizes, int n_in,
                              void* d_out, int out_size, void* d_ws, size_t ws_size,
                              hipStream_t stream) {
  const float* x      = (const float*)d_in[0];
  const float* tok_ng = (const float*)d_in[1];
  const float* tok_nb = (const float*)d_in[2];
  const float* tok_w1 = (const float*)d_in[3];
  const float* tok_b1 = (const float*)d_in[4];
  const float* tok_w2 = (const float*)d_in[5];
  const float* tok_b2 = (const float*)d_in[6];
  const float* ln1_g  = (const float*)d_in[7];
  const float* ln1_b  = (const float*)d_in[8];
  const float* w_qkv  = (const float*)d_in[9];
  const float* temp   = (const float*)d_in[10];
  const float* loc_w  = (const float*)d_in[11];
  const float* w_proj = (const float*)d_in[12];
  const float* b_proj = (const float*)d_in[13];
  const float* ls1    = (const float*)d_in[14];
  const float* ln2_g  = (const float*)d_in[15];
  const float* ln2_b  = (const float*)d_in[16];
  const float* ff_w1  = (const float*)d_in[17];
  const float* ff_b1  = (const float*)d_in[18];
  const float* ff_w2  = (const float*)d_in[19];
  const float* ff_b2  = (const float*)d_in[20];
  const float* ls2    = (const float*)d_in[21];
  float* out = (float*)d_out;

  char* ws = (char*)d_ws;
  size_t off = 0;
  auto alloc = [&](size_t bytes) -> void* {
    void* p = ws + off; off += (bytes + 255) & ~(size_t)255; return p;
  };
  // weights (persistent per launch)
  u16* w1T   = (u16*)alloc(768UL * 3840 * 2);
  u16* w2T   = (u16*)alloc(384UL * 768 * 2);
  u16* qkvT  = (u16*)alloc(8UL * 1152 * 384 * 2);
  u16* projT = (u16*)alloc(8UL * 384 * 384 * 2);
  u16* f1T   = (u16*)alloc(8UL * 1536 * 384 * 2);
  u16* f2T   = (u16*)alloc(8UL * 384 * 1536 * 2);
  // persistent activation
  float* h   = (float*)alloc((size_t)MP * 384 * 4);
  // regB: h1 (embed) OR { ypad/yff | ob } (blocks)
  char* regB = (char*)alloc(22500000);
  u16* h1   = (u16*)regB;                               // [MP][768] bf16 (embed)
  u16* ypad = (u16*)regB;                               // [MQ][384] = 11.01MB
  u16* yff  = (u16*)regB;                               // [MP][384] (ln2 out)
  u16* ob   = (u16*)(regB + 11010048);                  // [MP][384] = 10.42MB
  // regA: Xlnc (embed) OR Qp/Kp/Vp (attn) OR f1b (ff)
  char* regA = (char*)alloc((size_t)MP * 1536 * 2);
  u16* Xlnc = (u16*)regA;
  u16* Qp   = (u16*)regA;                               // 96*896*64*2  = 11.0MB
  u16* Kp   = (u16*)(regA + 11010048);                  // 96*14*8192   = 11.0MB
  u16* Vp   = (u16*)(regA + 22020096);                  // 11.0MB (33MB <= 41.7MB)
  u16* f1b  = (u16*)regA;
  (void)in_sizes; (void)n_in; (void)out_size;

  if (off > ws_size) return;  // diagnostic: leaves d_out untouched -> absmax ~2.5

  // weight transposes (fp32 [K][N] -> bf16 [N][K])
  transpose_conv<<<dim3(24, 120, 1), 256, 0, stream>>>(tok_w1, w1T, 3840, 768);
  transpose_conv<<<dim3(12, 24, 1), 256, 0, stream>>>(tok_w2, w2T, 768, 384);
  transpose_conv<<<dim3(36, 12, 8), 256, 0, stream>>>(w_qkv, qkvT, 384, 1152);
  transpose_conv<<<dim3(12, 12, 8), 256, 0, stream>>>(w_proj, projT, 384, 384);
  transpose_conv<<<dim3(48, 12, 8), 256, 0, stream>>>(ff_w1, f1T, 384, 1536);
  transpose_conv<<<dim3(12, 48, 8), 256, 0, stream>>>(ff_w2, f2T, 1536, 384);

  // patch embed + LN(3840) + first GEMM, chunked through Xlnc
  for (int m = 0; m < MP; m += CM) {
    int rows = MP - m; if (rows > CM) rows = CM;
    patch_ln<<<rows, 256, 0, stream>>>(x, tok_ng, tok_nb, Xlnc, m);
    gemm_bt<1, 128, 32><<<dim3(6, rows / 128), 256, 0, stream>>>(Xlnc, w1T, 768, 3840,
        tok_b1, nullptr, nullptr, h1 + (size_t)m * 768, nullptr);
  }
  gemm_bt<2, 64, 64><<<dim3(3, MP / 64), 256, 0, stream>>>(h1, w2T, 384, 768, tok_b2,
      nullptr, nullptr, nullptr, h);

  for (int d = 0; d < 8; ++d) {
    ln384p<<<MQ / 4, 256, 0, stream>>>(h, ln1_g + d * E_, ln1_b + d * E_, ypad);
    gemm_qkv<<<dim3(9, 112), 256, 0, stream>>>(ypad, qkvT + (size_t)d * 1152 * 384, Qp, Kp, Vp);
    attn_sp<<<672, 512, 0, stream>>>(Qp, Kp, Vp, temp + d * NH_, loc_w + d * NH_, ob);
    gemm_bt<3, 64, 64><<<dim3(3, MP / 64), 256, 0, stream>>>(ob, projT + (size_t)d * 384 * 384,
        384, 384, b_proj + d * E_, ls1 + d * E_, h, nullptr, nullptr);
    ln384<<<MP / 4, 256, 0, stream>>>(h, ln2_g + d * E_, ln2_b + d * E_, yff);
    gemm_bt<1, 128, 32><<<dim3(12, MP / 128), 256, 0, stream>>>(yff, f1T + (size_t)d * 1536 * 384,
        1536, 384, ff_b1 + d * 1536, nullptr, nullptr, f1b, nullptr);
    if (d < 7)
      gemm_bt<3, 64, 64><<<dim3(3, MP / 64), 256, 0, stream>>>(f1b, f2T + (size_t)d * 384 * 1536,
          384, 1536, ff_b2 + d * E_, ls2 + d * E_, h, nullptr, nullptr);
    else
      gemm_bt<4, 64, 64><<<dim3(3, MP / 64), 256, 0, stream>>>(f1b, f2T + (size_t)d * 384 * 1536,
          384, 1536, ff_b2 + d * E_, ls2 + d * E_, h, nullptr, out);
  }
}

// Round 22
// 1642.615 us; speedup vs baseline: 1.0838x; 1.0307x over previous
//
#include <hip/hip_runtime.h>
#include <math.h>

typedef __attribute__((ext_vector_type(8))) short short8;
typedef __attribute__((ext_vector_type(4))) float f32x4;
typedef unsigned short u16;

#define NTOK 841
#define GRID_H 29
#define E_ 384
#define NH_ 6
#define MROWS 13456
#define MP 13568
#define MQ 14336
#define CM 5120

__device__ __forceinline__ u16 f2bf(float f) {
  union { float f; unsigned int u; } c; c.f = f;
  unsigned int u = c.u;
  return (u16)((u + 0x7fffu + ((u >> 16) & 1u)) >> 16);
}

__device__ __forceinline__ float bf2f(u16 b) {
  union { unsigned int u; float f; } c; c.u = ((unsigned int)b) << 16; return c.f;
}

__device__ __forceinline__ float gelu_exact(float v) {
  return 0.5f * v * (1.f + erff(v * 0.70710678118654752440f));
}

__device__ __forceinline__ float fexp2(float x) {
  float r; asm("v_exp_f32 %0, %1" : "=v"(r) : "v"(x)); return r;
}

// byte offset in a [rows][64]-bf16 tile (128B/row), 16B-chunk XOR swizzle
__device__ __forceinline__ int swz64(int row, int col) {
  return row * 128 + ((((col >> 3) ^ (row & 7)) << 4) | ((col & 7) << 1));
}

// ---------------- transpose + fp32->bf16 convert: in [K][N] -> out [N][K] ----
__global__ __launch_bounds__(256) void transpose_conv(const float* __restrict__ in,
    u16* __restrict__ out, int K, int N) {
  __shared__ float tile[32][33];
  size_t zo = (size_t)blockIdx.z * K * N;
  const float* inp = in + zo;
  u16* outp = out + zo;
  int n0 = blockIdx.x * 32, k0 = blockIdx.y * 32;
  int tx = threadIdx.x & 31, ty = threadIdx.x >> 5;
  #pragma unroll
  for (int r = ty; r < 32; r += 8) tile[r][tx] = inp[(size_t)(k0 + r) * N + n0 + tx];
  __syncthreads();
  #pragma unroll
  for (int r = ty; r < 32; r += 8) outp[(size_t)(n0 + r) * K + k0 + tx] = f2bf(tile[tx][r]);
}

// ---------------- fused 5-shift patchify + LayerNorm(3840) -> bf16 ----------
__global__ __launch_bounds__(256) void patch_ln(const float* __restrict__ x,
    const float* __restrict__ g, const float* __restrict__ bsh, u16* __restrict__ out,
    int t0) {
  int t = t0 + blockIdx.x;
  int tid = threadIdx.x;
  u16* orow = out + (size_t)blockIdx.x * 3840;
  if (t >= MROWS) {
    #pragma unroll
    for (int j = 0; j < 15; ++j) orow[tid + j * 256] = 0;  // bf16 zero
    return;
  }
  int bimg = t / NTOK, n = t % NTOK;
  int gy = n / GRID_H, gx = n % GRID_H;
  float vals[15];
  float s1 = 0.f, s2 = 0.f;
  #pragma unroll
  for (int j = 0; j < 15; ++j) {
    int cout = tid + j * 256;
    int s = cout / 768, rem = cout % 768;
    int c = rem / 256, rem2 = rem % 256;
    int py = rem2 / 16, px = rem2 % 16;
    int dy = (s == 1 ? 8 : 0) - (s == 2 ? 8 : 0);
    int dx = (s == 3 ? 8 : 0) - (s == 4 ? 8 : 0);
    int Y = gy * 16 + py - dy;
    int X = gx * 16 + px - dx;
    float v = 0.f;
    if (Y >= 0 && Y < 464 && X >= 0 && X < 464)
      v = x[(((size_t)bimg * 3 + c) * 464 + Y) * 464 + X];
    vals[j] = v;
    s1 += v; s2 += v * v;
  }
  #pragma unroll
  for (int m = 1; m < 64; m <<= 1) { s1 += __shfl_xor(s1, m); s2 += __shfl_xor(s2, m); }
  __shared__ float ws1[4], ws2[4];
  int wid = tid >> 6;
  if ((tid & 63) == 0) { ws1[wid] = s1; ws2[wid] = s2; }
  __syncthreads();
  s1 = ws1[0] + ws1[1] + ws1[2] + ws1[3];
  s2 = ws2[0] + ws2[1] + ws2[2] + ws2[3];
  float mean = s1 * (1.f / 3840.f);
  float var = s2 * (1.f / 3840.f) - mean * mean;
  float rs = rsqrtf(var + 1e-5f);
  #pragma unroll
  for (int j = 0; j < 15; ++j) {
    int cout = tid + j * 256;
    orow[cout] = f2bf((vals[j] - mean) * rs * g[cout] + bsh[cout]);
  }
}

// ---------------- LayerNorm(384) fp32 -> bf16 (packed MP rows) ---------------
__global__ __launch_bounds__(256) void ln384(const float* __restrict__ h,
    const float* __restrict__ g, const float* __restrict__ bsh, u16* __restrict__ y) {
  int row = blockIdx.x * 4 + (threadIdx.x >> 6);
  int lane = threadIdx.x & 63;
  const float* hr = h + (size_t)row * E_;
  float v[6];
  float s1 = 0.f;
  #pragma unroll
  for (int j = 0; j < 6; ++j) { v[j] = hr[lane + j * 64]; s1 += v[j]; }
  #pragma unroll
  for (int m = 1; m < 64; m <<= 1) s1 += __shfl_xor(s1, m);
  float mean = s1 * (1.f / 384.f);
  float s2 = 0.f;
  #pragma unroll
  for (int j = 0; j < 6; ++j) { float d = v[j] - mean; s2 += d * d; }
  #pragma unroll
  for (int m = 1; m < 64; m <<= 1) s2 += __shfl_xor(s2, m);
  float rs = rsqrtf(s2 * (1.f / 384.f) + 1e-5f);
  u16* yr = y + (size_t)row * E_;
  #pragma unroll
  for (int j = 0; j < 6; ++j) {
    int c = lane + j * 64;
    yr[c] = f2bf((v[j] - mean) * rs * g[c] + bsh[c]);
  }
}

// ---------------- LayerNorm(384) -> 896-padded bf16 (zeros on pad rows) ------
__global__ __launch_bounds__(256) void ln384p(const float* __restrict__ h,
    const float* __restrict__ g, const float* __restrict__ bsh, u16* __restrict__ yp) {
  int rowp = blockIdx.x * 4 + (threadIdx.x >> 6);
  int lane = threadIdx.x & 63;
  int bg = rowp / 896, tk = rowp - bg * 896;
  u16* yr = yp + (size_t)rowp * E_;
  if (tk >= NTOK) {
    #pragma unroll
    for (int j = 0; j < 6; ++j) yr[lane + j * 64] = 0;
    return;
  }
  const float* hr = h + (size_t)(bg * NTOK + tk) * E_;
  float v[6];
  float s1 = 0.f;
  #pragma unroll
  for (int j = 0; j < 6; ++j) { v[j] = hr[lane + j * 64]; s1 += v[j]; }
  #pragma unroll
  for (int m = 1; m < 64; m <<= 1) s1 += __shfl_xor(s1, m);
  float mean = s1 * (1.f / 384.f);
  float s2 = 0.f;
  #pragma unroll
  for (int j = 0; j < 6; ++j) { float d = v[j] - mean; s2 += d * d; }
  #pragma unroll
  for (int m = 1; m < 64; m <<= 1) s2 += __shfl_xor(s2, m);
  float rs = rsqrtf(s2 * (1.f / 384.f) + 1e-5f);
  #pragma unroll
  for (int j = 0; j < 6; ++j) {
    int c = lane + j * 64;
    yr[c] = f2bf((v[j] - mean) * rs * g[c] + bsh[c]);
  }
}

// ---------------- bf16 MFMA GEMM, min-2-phase pipelined (T3+T4) --------------
// EPI: 1 = bf16 gelu(acc+bias), LDS-staged coalesced out; 2 = f32 acc+bias;
//      3 = resid[m][n] += lscale[n]*(acc+bias[n]);
//      4 = outf[m][n] = resid[m][n] + lscale[n]*(acc+bias[n]) (final, m<MROWS)
// BK: 64 (8-chunk swizzle) or 32 (4-chunk swizzle, halves LDS for occupancy)
template<int EPI, int TM, int BK>
__global__ __launch_bounds__(256) void gemm_bt(
    const u16* __restrict__ A, const u16* __restrict__ BT,
    int N, int K,
    const float* __restrict__ bias, const float* __restrict__ lscale,
    float* __restrict__ resid, u16* __restrict__ outb, float* __restrict__ outf) {
  constexpr int MI = TM / 32;
  constexpr int BUF = (TM + 128) * BK;              // shorts per buffer
  constexpr int SM1 = 2 * BUF * 2;
  constexpr int SM2 = (EPI == 1) ? TM * 136 * 2 : 0;
  constexpr int SMEM = SM1 > SM2 ? SM1 : SM2;
  __shared__ alignas(16) char smem[SMEM];
  short* As = (short*)smem;
  // bijective XCD swizzle (m204)
  const int gx = gridDim.x;
  const int nwg = gx * gridDim.y;
  int L = blockIdx.x + blockIdx.y * gx;
  int q8 = nwg >> 3, r8 = nwg & 7, xcd = L & 7, pos = L >> 3;
  int L2 = (xcd < r8 ? xcd * (q8 + 1) : r8 * (q8 + 1) + (xcd - r8) * q8) + pos;
  const int m0 = (L2 / gx) * TM, n0 = (L2 % gx) * 128;
  const int tid = threadIdx.x;
  const int lane = tid & 63, wid = tid >> 6;
  const int wm = wid >> 1, wn = wid & 1;
  f32x4 acc[MI][4] = {};
  const int nkt = K / BK;

  auto stage = [&](int b, int kt) {
    short* Ab = As + b * BUF;
    short* Bb = Ab + TM * BK;
    const int k0 = kt * BK;
    if constexpr (BK == 64) {
      const int rowl = lane >> 3;
      const int colc = (((lane & 7) ^ (rowl & 7)) << 3);
      #pragma unroll
      for (int i = 0; i < TM / 32; ++i) {
        int chunk = i * 4 + wid;
        const u16* ga = A + (size_t)(m0 + chunk * 8 + rowl) * K + k0 + colc;
        __builtin_amdgcn_global_load_lds((const __attribute__((address_space(1))) void*)ga,
            (__attribute__((address_space(3))) void*)(Ab + (chunk << 9)), 16, 0, 0);
      }
      #pragma unroll
      for (int i = 0; i < 4; ++i) {
        int chunk = i * 4 + wid;
        const u16* gb = BT + (size_t)(n0 + chunk * 8 + rowl) * K + k0 + colc;
        __builtin_amdgcn_global_load_lds((const __attribute__((address_space(1))) void*)gb,
            (__attribute__((address_space(3))) void*)(Bb + (chunk << 9)), 16, 0, 0);
      }
    } else {
      const int rowl = lane >> 2;                 // 16 rows per wave-slab
      const int colc = (((lane & 3) ^ (rowl & 3)) << 3);
      #pragma unroll
      for (int i = 0; i < TM / 64; ++i) {
        int rbase = i * 64 + wid * 16;
        const u16* ga = A + (size_t)(m0 + rbase + rowl) * K + k0 + colc;
        __builtin_amdgcn_global_load_lds((const __attribute__((address_space(1))) void*)ga,
            (__attribute__((address_space(3))) void*)(Ab + rbase * 32), 16, 0, 0);
      }
      #pragma unroll
      for (int i = 0; i < 2; ++i) {
        int rbase = i * 64 + wid * 16;
        const u16* gb = BT + (size_t)(n0 + rbase + rowl) * K + k0 + colc;
        __builtin_amdgcn_global_load_lds((const __attribute__((address_space(1))) void*)gb,
            (__attribute__((address_space(3))) void*)(Bb + rbase * 32), 16, 0, 0);
      }
    }
  };

  const int lg = lane >> 4;
  stage(0, 0);
  for (int kt = 0; kt < nkt; ++kt) {
    const int cur = kt & 1;
    if (kt + 1 < nkt) {
      stage(cur ^ 1, kt + 1);
      // wait own current-tile loads (allow next tile's NL in flight)
      if constexpr (BK == 64) {
        if constexpr (TM == 128) asm volatile("s_waitcnt vmcnt(8)" ::: "memory");
        else                     asm volatile("s_waitcnt vmcnt(6)" ::: "memory");
      } else {
        if constexpr (TM == 128) asm volatile("s_waitcnt vmcnt(4)" ::: "memory");
        else                     asm volatile("s_waitcnt vmcnt(3)" ::: "memory");
      }
    } else {
      asm volatile("s_waitcnt vmcnt(0)" ::: "memory");
    }
    __builtin_amdgcn_s_barrier();       // all waves' current tile complete
    __builtin_amdgcn_sched_barrier(0);
    short* Ab = As + cur * BUF;
    short* Bb = Ab + TM * BK;
    #pragma unroll
    for (int kk = 0; kk < BK / 32; ++kk) {
      short8 a[MI], bfr[4];
      #pragma unroll
      for (int mi = 0; mi < MI; ++mi) {
        int ra = wm * (TM / 2) + mi * 16 + (lane & 15);
        int off = (BK == 64) ? ((((kk << 2) | lg) ^ (ra & 7)) << 3)
                             : ((lg ^ (ra & 3)) << 3);
        a[mi] = *(const short8*)(Ab + ra * BK + off);
      }
      #pragma unroll
      for (int nj = 0; nj < 4; ++nj) {
        int rb = wn * 64 + nj * 16 + (lane & 15);
        int off = (BK == 64) ? ((((kk << 2) | lg) ^ (rb & 7)) << 3)
                             : ((lg ^ (rb & 3)) << 3);
        bfr[nj] = *(const short8*)(Bb + rb * BK + off);
      }
      #pragma unroll
      for (int mi = 0; mi < MI; ++mi)
        #pragma unroll
        for (int nj = 0; nj < 4; ++nj)
          acc[mi][nj] = __builtin_amdgcn_mfma_f32_16x16x32_bf16(a[mi], bfr[nj], acc[mi][nj], 0, 0, 0);
    }
    __builtin_amdgcn_s_barrier();       // reads of 'cur' done before its overwrite
  }
  const int rrow = (lane >> 4) << 2;
  const int ccol = lane & 15;
  if (EPI == 1) {
    // stage C in LDS, write coalesced full rows
    u16* Cs = (u16*)smem;
    __syncthreads();
    #pragma unroll
    for (int mi = 0; mi < MI; ++mi)
      #pragma unroll
      for (int nj = 0; nj < 4; ++nj) {
        int cc = wn * 64 + nj * 16 + ccol;
        float bi = bias[n0 + cc];
        #pragma unroll
        for (int r = 0; r < 4; ++r) {
          int cr = wm * (TM / 2) + mi * 16 + rrow + r;
          Cs[cr * 136 + cc] = f2bf(gelu_exact(acc[mi][nj][r] + bi));
        }
      }
    __syncthreads();
    #pragma unroll
    for (int it = 0; it < TM / 16; ++it) {
      int idx = it * 256 + tid;
      int orow = idx >> 4, c = idx & 15;
      short8 v = *(const short8*)(Cs + orow * 136 + c * 8);
      *(short8*)(outb + (size_t)(m0 + orow) * N + n0 + c * 8) = v;
    }
    return;
  }
  #pragma unroll
  for (int mi = 0; mi < MI; ++mi)
    #pragma unroll
    for (int nj = 0; nj < 4; ++nj) {
      int gn = n0 + wn * 64 + nj * 16 + ccol;
      #pragma unroll
      for (int r = 0; r < 4; ++r) {
        int gm = m0 + wm * (TM / 2) + mi * 16 + rrow + r;
        float v = acc[mi][nj][r];
        if (EPI == 2) {
          outf[(size_t)gm * N + gn] = v + bias[gn];
        } else if (EPI == 3) {
          float* p = resid + (size_t)gm * N + gn;
          *p = *p + lscale[gn] * (v + bias[gn]);
        } else {
          if (gm < MROWS)
            outf[(size_t)gm * N + gn] =
                resid[(size_t)gm * N + gn] + lscale[gn] * (v + bias[gn]);
        }
      }
    }
}

// ---------------- qkv GEMM over padded-896 rows, pipelined, swizzled out -----
__global__ __launch_bounds__(256) void gemm_qkv(
    const u16* __restrict__ A, const u16* __restrict__ BT,
    u16* __restrict__ Qp, u16* __restrict__ Kp, u16* __restrict__ Vp) {
  const int K = 384;
  constexpr int BUF = 256 * 64;
  __shared__ alignas(16) char smem[2 * BUF * 2];   // 64KB dbuf; Cs aliases
  short* As = (short*)smem;
  // XCD swizzle over 1008 blocks (1008 = 8*126)
  int L = blockIdx.x + blockIdx.y * 9;
  int L2 = (L & 7) * 126 + (L >> 3);
  const int m0 = (L2 / 9) * 128, n0 = (L2 % 9) * 128;
  const int tid = threadIdx.x;
  const int lane = tid & 63, wid = tid >> 6;
  const int wm = wid >> 1, wn = wid & 1;
  const int rowl = lane >> 3;
  const int colc = (((lane & 7) ^ (rowl & 7)) << 3);
  f32x4 acc[4][4] = {};

  auto stage = [&](int b, int kt) {
    short* Ab = As + b * BUF;
    short* Bb = Ab + 128 * 64;
    const int k0 = kt * 64;
    #pragma unroll
    for (int i = 0; i < 4; ++i) {
      int chunk = i * 4 + wid;
      const u16* ga = A + (size_t)(m0 + chunk * 8 + rowl) * K + k0 + colc;
      __builtin_amdgcn_global_load_lds((const __attribute__((address_space(1))) void*)ga,
          (__attribute__((address_space(3))) void*)(Ab + (chunk << 9)), 16, 0, 0);
      const u16* gb = BT + (size_t)(n0 + chunk * 8 + rowl) * K + k0 + colc;
      __builtin_amdgcn_global_load_lds((const __attribute__((address_space(1))) void*)gb,
          (__attribute__((address_space(3))) void*)(Bb + (chunk << 9)), 16, 0, 0);
    }
  };

  stage(0, 0);
  for (int kt = 0; kt < 6; ++kt) {
    const int cur = kt & 1;
    if (kt + 1 < 6) {
      stage(cur ^ 1, kt + 1);
      asm volatile("s_waitcnt vmcnt(8)" ::: "memory");
    } else {
      asm volatile("s_waitcnt vmcnt(0)" ::: "memory");
    }
    __builtin_amdgcn_s_barrier();
    __builtin_amdgcn_sched_barrier(0);
    short* Ab = As + cur * BUF;
    short* Bb = Ab + 128 * 64;
    #pragma unroll
    for (int kk = 0; kk < 2; ++kk) {
      short8 a[4], bfr[4];
      #pragma unroll
      for (int mi = 0; mi < 4; ++mi) {
        int ra = wm * 64 + mi * 16 + (lane & 15);
        a[mi] = *(const short8*)(Ab + ra * 64 + ((((kk << 2) | (lane >> 4)) ^ (ra & 7)) << 3));
      }
      #pragma unroll
      for (int nj = 0; nj < 4; ++nj) {
        int rb = wn * 64 + nj * 16 + (lane & 15);
        bfr[nj] = *(const short8*)(Bb + rb * 64 + ((((kk << 2) | (lane >> 4)) ^ (rb & 7)) << 3));
      }
      #pragma unroll
      for (int mi = 0; mi < 4; ++mi)
        #pragma unroll
        for (int nj = 0; nj < 4; ++nj)
          acc[mi][nj] = __builtin_amdgcn_mfma_f32_16x16x32_bf16(a[mi], bfr[nj], acc[mi][nj], 0, 0, 0);
    }
    __builtin_amdgcn_s_barrier();
  }
  // epilogue: stage in LDS ([tok][col] for Q/K, transposed [col][tok] for V)
  const int seg = n0 / 384;                 // 0=Q 1=K 2=V (block-uniform)
  const int h0 = (n0 - seg * 384) >> 6;     // head pair base: 0,2,4
  const int bg = m0 / 896;
  const int tk0 = m0 - bg * 896;            // 0..768, 64-tile aligned
  const int rrow = (lane >> 4) << 2;
  const int ccol = lane & 15;
  u16* Cs = (u16*)smem;
  __syncthreads();
  #pragma unroll
  for (int mi = 0; mi < 4; ++mi)
    #pragma unroll
    for (int nj = 0; nj < 4; ++nj) {
      int cc = wn * 64 + nj * 16 + ccol;
      #pragma unroll
      for (int r = 0; r < 4; ++r) {
        int cr = wm * 64 + mi * 16 + rrow + r;
        u16 bv = f2bf(acc[mi][nj][r]);
        if (seg == 2) Cs[cc * 136 + cr] = bv;
        else          Cs[cr * 136 + cc] = bv;
      }
    }
  __syncthreads();
  // write out 256 rows x 128B, full-line short8 stores
  #pragma unroll
  for (int i = 0; i < 8; ++i) {
    int idx = i * 256 + tid;
    int c = idx & 7;                 // 16B chunk within 128B row
    int orow = idx >> 3;             // 0..255
    int hs = orow >> 7;              // head select
    int rl = orow & 127;
    size_t bh = (size_t)(bg * 6 + h0 + hs);
    if (seg == 2) {
      int tile_l = rl >> 6, hd = rl & 63;
      short8 v = *(const short8*)(Cs + (hs * 64 + hd) * 136 + tile_l * 64 + c * 8);
      int tile = (tk0 >> 6) + tile_l;
      *(short8*)(Vp + bh * 57344 + tile * 4096 + hd * 64 + ((c ^ (hd & 7)) << 3)) = v;
    } else {
      short8 v = *(const short8*)(Cs + rl * 136 + hs * 64 + c * 8);
      if (seg == 0) {
        *(short8*)(Qp + (bh * 896 + tk0 + rl) * 64 + c * 8) = v;
      } else {
        int tok = tk0 + rl;
        *(short8*)(Kp + bh * 57344 + (tok >> 6) * 4096 + (tok & 63) * 64 + ((c ^ (tok & 7)) << 3)) = v;
      }
    }
  }
}

// ---------------- single-pass flash attention, 8 waves / 128 q-rows ----------
__global__ __launch_bounds__(512) void attn_sp(const u16* __restrict__ Qp,
    const u16* __restrict__ Kp, const u16* __restrict__ Vp,
    const float* __restrict__ temp_d, const float* __restrict__ locw_d,
    u16* __restrict__ ob) {
  // 1D grid = hardware dispatch order; bijective XCD swizzle: 672 = 8*84.
  int Lw = blockIdx.x;
  int L2 = (Lw & 7) * 84 + (Lw >> 3);
  const int bh = L2 / 7, qp = L2 % 7;       // qp = 128-row q-block
  const int hh = bh % NH_;
  const int tid = threadIdx.x, lane = tid & 63, w = tid >> 6;   // w in [0,8)
  const int lg = lane >> 4, lc = lane & 15;
  const float LOG2E = 1.44269504088896f;
  const float scale = __expf(temp_d[hh]) * LOG2E;   // exp2-domain
  const float lwh = locw_d[hh] * LOG2E * -0.5f;

  __shared__ alignas(16) char ktl[2][8192];       // K tiles [tok][hd], swizzled, dbuf
  __shared__ alignas(16) char vtl[2][8192];       // V^T tiles [hd][tok], swizzled, dbuf
  __shared__ alignas(16) char pl[8][2048];        // per-wave P [q][tok], swizzled
  __shared__ float yx2[896 * 2];                  // token coords (y,x)

  for (int j = tid; j < 896; j += 512) {
    unsigned jc = j < NTOK ? (unsigned)j : (NTOK - 1);
    yx2[j * 2]     = (float)(jc / 29u) * (1.f / 28.f);
    yx2[j * 2 + 1] = (float)(jc % 29u) * (1.f / 28.f);
  }

  // Q fragments from head-contiguous Qp (this wave's 16-row slice of 128)
  const char* qb = (const char*)(Qp + ((size_t)bh * 896 + qp * 128) * 64);
  short8 qf0 = *(const short8*)(qb + (w * 16 + lc) * 128 + lg * 16);
  short8 qf1 = *(const short8*)(qb + (w * 16 + lc) * 128 + 64 + lg * 16);

  const char* kbase = (const char*)Kp + (size_t)bh * 14 * 8192;
  const char* vbase = (const char*)Vp + (size_t)bh * 14 * 8192;

  // staging: 8 waves cover 8KB each of K and V (1 load per tensor per thread)
  auto stage = [&](int b, int kt) {
    int off = w * 1024;
    __builtin_amdgcn_global_load_lds(
        (const __attribute__((address_space(1))) void*)(kbase + kt * 8192 + off + lane * 16),
        (__attribute__((address_space(3))) void*)(ktl[b] + off), 16, 0, 0);
    __builtin_amdgcn_global_load_lds(
        (const __attribute__((address_space(1))) void*)(vbase + kt * 8192 + off + lane * 16),
        (__attribute__((address_space(3))) void*)(vtl[b] + off), 16, 0, 0);
  };

  f32x4 of[4] = {};
  float mrow[4], psum[4];
  #pragma unroll
  for (int r = 0; r < 4; ++r) { mrow[r] = -3e38f; psum[r] = 0.f; }

  stage(0, 0);
  asm volatile("s_waitcnt vmcnt(0)" ::: "memory");
  __syncthreads();

  // per-row coord weights (row-const lwh*|q|^2 dropped: softmax-invariant)
  float qyw[4], qxw[4];
  #pragma unroll
  for (int r = 0; r < 4; ++r) {
    int iq = qp * 128 + w * 16 + (lg << 2) + r;     // <= 895
    qyw[r] = -2.f * lwh * yx2[iq * 2];
    qxw[r] = -2.f * lwh * yx2[iq * 2 + 1];
  }

  for (int kt = 0; kt < 14; ++kt) {
    const int b = kt & 1;
    if (kt < 13) stage(b ^ 1, kt + 1);  // issue next-tile loads early (T14)

    const char* kb = ktl[b];
    const char* vb = vtl[b];
    f32x4 sf[4];
    __builtin_amdgcn_s_setprio(1);
    #pragma unroll
    for (int nt = 0; nt < 4; ++nt) {
      short8 kf0 = *(const short8*)(kb + swz64(nt * 16 + lc, lg << 3));
      short8 kf1 = *(const short8*)(kb + swz64(nt * 16 + lc, 32 + (lg << 3)));
      f32x4 z = {0.f, 0.f, 0.f, 0.f};
      z = __builtin_amdgcn_mfma_f32_16x16x32_bf16(qf0, kf0, z, 0, 0, 0);
      z = __builtin_amdgcn_mfma_f32_16x16x32_bf16(qf1, kf1, z, 0, 0, 0);
      sf[nt] = z;
    }
    __builtin_amdgcn_s_setprio(0);

    const int jb = kt * 64;
    #pragma unroll
    for (int nt = 0; nt < 4; ++nt) {
      int j = jb + nt * 16 + lc;
      float jy = yx2[j * 2], jx = yx2[j * 2 + 1];
      float bc = lwh * (jy * jy + jx * jx);
      #pragma unroll
      for (int r = 0; r < 4; ++r) {
        float val = sf[nt][r] * scale + bc;
        val += qyw[r] * jy;
        val += qxw[r] * jx;
        sf[nt][r] = val;
      }
    }
    if (jb + 64 > NTOK) {               // tail tile only (uniform branch)
      #pragma unroll
      for (int nt = 0; nt < 4; ++nt) {
        if (jb + nt * 16 + lc >= NTOK) {
          sf[nt][0] = -3e38f; sf[nt][1] = -3e38f; sf[nt][2] = -3e38f; sf[nt][3] = -3e38f;
        }
      }
    }

    float lm[4];
    #pragma unroll
    for (int r = 0; r < 4; ++r)
      lm[r] = fmaxf(fmaxf(sf[0][r], sf[1][r]), fmaxf(sf[2][r], sf[3][r]));
    bool trig = (lm[0] > mrow[0] + 12.f) | (lm[1] > mrow[1] + 12.f) |
                (lm[2] > mrow[2] + 12.f) | (lm[3] > mrow[3] + 12.f);
    if (__any(trig)) {
      #pragma unroll
      for (int r = 0; r < 4; ++r) {
        float tm = lm[r];
        #pragma unroll
        for (int m = 1; m < 16; m <<= 1) tm = fmaxf(tm, __shfl_xor(tm, m));
        float mnew = fmaxf(mrow[r], tm);
        float alpha = fexp2(mrow[r] - mnew);
        psum[r] *= alpha;
        of[0][r] *= alpha; of[1][r] *= alpha; of[2][r] *= alpha; of[3][r] *= alpha;
        mrow[r] = mnew;
      }
    }

    // exp2 + per-lane psum + packed bf16 conversion (v_cvt_pk, RNE)
    char* plw = pl[w];
    #pragma unroll
    for (int nt = 0; nt < 4; ++nt) {
      float p0 = fexp2(sf[nt][0] - mrow[0]);
      float p1 = fexp2(sf[nt][1] - mrow[1]);
      float p2 = fexp2(sf[nt][2] - mrow[2]);
      float p3 = fexp2(sf[nt][3] - mrow[3]);
      psum[0] += p0; psum[1] += p1; psum[2] += p2; psum[3] += p3;
      unsigned w01, w23;
      asm("v_cvt_pk_bf16_f32 %0, %1, %2" : "=v"(w01) : "v"(p0), "v"(p1));
      asm("v_cvt_pk_bf16_f32 %0, %1, %2" : "=v"(w23) : "v"(p2), "v"(p3));
      int col = nt * 16 + lc;
      *(u16*)(plw + swz64((lg << 2) + 0, col)) = (u16)w01;
      *(u16*)(plw + swz64((lg << 2) + 1, col)) = (u16)(w01 >> 16);
      *(u16*)(plw + swz64((lg << 2) + 2, col)) = (u16)w23;
      *(u16*)(plw + swz64((lg << 2) + 3, col)) = (u16)(w23 >> 16);
    }
    asm volatile("s_waitcnt lgkmcnt(0)" ::: "memory");
    __builtin_amdgcn_sched_barrier(0);
    short8 pa[2];
    #pragma unroll
    for (int t = 0; t < 2; ++t)
      pa[t] = *(const short8*)(plw + swz64(lc, t * 32 + (lg << 3)));

    __builtin_amdgcn_s_setprio(1);
    #pragma unroll
    for (int n2 = 0; n2 < 4; ++n2) {
      f32x4 accv = of[n2];
      #pragma unroll
      for (int t = 0; t < 2; ++t) {
        short8 vf = *(const short8*)(vb + swz64(n2 * 16 + lc, t * 32 + (lg << 3)));
        accv = __builtin_amdgcn_mfma_f32_16x16x32_bf16(pa[t], vf, accv, 0, 0, 0);
      }
      of[n2] = accv;
    }
    __builtin_amdgcn_s_setprio(0);

    if (kt < 13) {
      // next tile ready (own loads done) + all my LDS reads of buf b sampled
      asm volatile("s_waitcnt vmcnt(0) lgkmcnt(0)" ::: "memory");
      __builtin_amdgcn_sched_barrier(0);
      __builtin_amdgcn_s_barrier();
    }
  }

  // final: per-row sum reduce (16 lanes) + normalized output
  const int bimg = bh / NH_;
  #pragma unroll
  for (int r = 0; r < 4; ++r) {
    float s = psum[r];
    #pragma unroll
    for (int m = 1; m < 16; m <<= 1) s += __shfl_xor(s, m);
    int iq = qp * 128 + w * 16 + (lg << 2) + r;
    if (iq < NTOK) {
      float rl = 1.f / s;
      #pragma unroll
      for (int n2 = 0; n2 < 4; ++n2)
        ob[((size_t)(bimg * NTOK + iq)) * E_ + hh * 64 + n2 * 16 + lc] =
            f2bf(of[n2][r] * rl);
    }
  }
}

extern "C" void kernel_launch(void* const* d_in, const int* in_sizes, int n_in,
                              void* d_out, int out_size, void* d_ws, size_t ws_size,
                              hipStream_t stream) {
  const float* x      = (const float*)d_in[0];
  const float* tok_ng = (const float*)d_in[1];
  const float* tok_nb = (const float*)d_in[2];
  const float* tok_w1 = (const float*)d_in[3];
  const float* tok_b1 = (const float*)d_in[4];
  const float* tok_w2 = (const float*)d_in[5];
  const float* tok_b2 = (const float*)d_in[6];
  const float* ln1_g  = (const float*)d_in[7];
  const float* ln1_b  = (const float*)d_in[8];
  const float* w_qkv  = (const float*)d_in[9];
  const float* temp   = (const float*)d_in[10];
  const float* loc_w  = (const float*)d_in[11];
  const float* w_proj = (const float*)d_in[12];
  const float* b_proj = (const float*)d_in[13];
  const float* ls1    = (const float*)d_in[14];
  const float* ln2_g  = (const float*)d_in[15];
  const float* ln2_b  = (const float*)d_in[16];
  const float* ff_w1  = (const float*)d_in[17];
  const float* ff_b1  = (const float*)d_in[18];
  const float* ff_w2  = (const float*)d_in[19];
  const float* ff_b2  = (const float*)d_in[20];
  const float* ls2    = (const float*)d_in[21];
  float* out = (float*)d_out;

  char* ws = (char*)d_ws;
  size_t off = 0;
  auto alloc = [&](size_t bytes) -> void* {
    void* p = ws + off; off += (bytes + 255) & ~(size_t)255; return p;
  };
  // weights (persistent per launch)
  u16* w1T   = (u16*)alloc(768UL * 3840 * 2);
  u16* w2T   = (u16*)alloc(384UL * 768 * 2);
  u16* qkvT  = (u16*)alloc(8UL * 1152 * 384 * 2);
  u16* projT = (u16*)alloc(8UL * 384 * 384 * 2);
  u16* f1T   = (u16*)alloc(8UL * 1536 * 384 * 2);
  u16* f2T   = (u16*)alloc(8UL * 384 * 1536 * 2);
  // persistent activation
  float* h   = (float*)alloc((size_t)MP * 384 * 4);
  // regB: h1 (embed) OR { ypad/yff | ob } (blocks)
  char* regB = (char*)alloc(22500000);
  u16* h1   = (u16*)regB;                               // [MP][768] bf16 (embed)
  u16* ypad = (u16*)regB;                               // [MQ][384] = 11.01MB
  u16* yff  = (u16*)regB;                               // [MP][384] (ln2 out)
  u16* ob   = (u16*)(regB + 11010048);                  // [MP][384] = 10.42MB
  // regA: Xlnc (embed) OR Qp/Kp/Vp (attn) OR f1b (ff)
  char* regA = (char*)alloc((size_t)MP * 1536 * 2);
  u16* Xlnc = (u16*)regA;
  u16* Qp   = (u16*)regA;                               // 96*896*64*2  = 11.0MB
  u16* Kp   = (u16*)(regA + 11010048);                  // 96*14*8192   = 11.0MB
  u16* Vp   = (u16*)(regA + 22020096);                  // 11.0MB (33MB <= 41.7MB)
  u16* f1b  = (u16*)regA;
  (void)in_sizes; (void)n_in; (void)out_size;

  if (off > ws_size) return;  // diagnostic: leaves d_out untouched -> absmax ~2.5

  // weight transposes (fp32 [K][N] -> bf16 [N][K])
  transpose_conv<<<dim3(24, 120, 1), 256, 0, stream>>>(tok_w1, w1T, 3840, 768);
  transpose_conv<<<dim3(12, 24, 1), 256, 0, stream>>>(tok_w2, w2T, 768, 384);
  transpose_conv<<<dim3(36, 12, 8), 256, 0, stream>>>(w_qkv, qkvT, 384, 1152);
  transpose_conv<<<dim3(12, 12, 8), 256, 0, stream>>>(w_proj, projT, 384, 384);
  transpose_conv<<<dim3(48, 12, 8), 256, 0, stream>>>(ff_w1, f1T, 384, 1536);
  transpose_conv<<<dim3(12, 48, 8), 256, 0, stream>>>(ff_w2, f2T, 1536, 384);

  // patch embed + LN(3840) + first GEMM, chunked through Xlnc
  // tok1 at TM=64: grid 12 x rows/64 -> 2x blocks (grid-limited kernel)
  for (int m = 0; m < MP; m += CM) {
    int rows = MP - m; if (rows > CM) rows = CM;
    patch_ln<<<rows, 256, 0, stream>>>(x, tok_ng, tok_nb, Xlnc, m);
    gemm_bt<1, 64, 64><<<dim3(6, rows / 64), 256, 0, stream>>>(Xlnc, w1T, 768, 3840,
        tok_b1, nullptr, nullptr, h1 + (size_t)m * 768, nullptr);
  }
  gemm_bt<2, 64, 64><<<dim3(3, MP / 64), 256, 0, stream>>>(h1, w2T, 384, 768, tok_b2,
      nullptr, nullptr, nullptr, h);

  for (int d = 0; d < 8; ++d) {
    ln384p<<<MQ / 4, 256, 0, stream>>>(h, ln1_g + d * E_, ln1_b + d * E_, ypad);
    gemm_qkv<<<dim3(9, 112), 256, 0, stream>>>(ypad, qkvT + (size_t)d * 1152 * 384, Qp, Kp, Vp);
    attn_sp<<<672, 512, 0, stream>>>(Qp, Kp, Vp, temp + d * NH_, loc_w + d * NH_, ob);
    gemm_bt<3, 64, 64><<<dim3(3, MP / 64), 256, 0, stream>>>(ob, projT + (size_t)d * 384 * 384,
        384, 384, b_proj + d * E_, ls1 + d * E_, h, nullptr, nullptr);
    ln384<<<MP / 4, 256, 0, stream>>>(h, ln2_g + d * E_, ln2_b + d * E_, yff);
    gemm_bt<1, 128, 32><<<dim3(12, MP / 128), 256, 0, stream>>>(yff, f1T + (size_t)d * 1536 * 384,
        1536, 384, ff_b1 + d * 1536, nullptr, nullptr, f1b, nullptr);
    if (d < 7)
      gemm_bt<3, 64, 64><<<dim3(3, MP / 64), 256, 0, stream>>>(f1b, f2T + (size_t)d * 384 * 1536,
          384, 1536, ff_b2 + d * E_, ls2 + d * E_, h, nullptr, nullptr);
    else
      gemm_bt<4, 64, 64><<<dim3(3, MP / 64), 256, 0, stream>>>(f1b, f2T + (size_t)d * 384 * 1536,
          384, 1536, ff_b2 + d * E_, ls2 + d * E_, h, nullptr, out);
  }
}

// Round 23
// 1598.408 us; speedup vs baseline: 1.1138x; 1.0277x over previous
//
#include <hip/hip_runtime.h>
#include <math.h>

typedef __attribute__((ext_vector_type(8))) short short8;
typedef __attribute__((ext_vector_type(4))) float f32x4;
typedef unsigned short u16;

#define NTOK 841
#define GRID_H 29
#define E_ 384
#define NH_ 6
#define MROWS 13456
#define MP 13568
#define MQ 14336
#define CM 5120

__device__ __forceinline__ u16 f2bf(float f) {
  union { float f; unsigned int u; } c; c.f = f;
  unsigned int u = c.u;
  return (u16)((u + 0x7fffu + ((u >> 16) & 1u)) >> 16);
}

__device__ __forceinline__ float bf2f(u16 b) {
  union { unsigned int u; float f; } c; c.u = ((unsigned int)b) << 16; return c.f;
}

__device__ __forceinline__ float gelu_exact(float v) {
  return 0.5f * v * (1.f + erff(v * 0.70710678118654752440f));
}

__device__ __forceinline__ float fexp2(float x) {
  float r; asm("v_exp_f32 %0, %1" : "=v"(r) : "v"(x)); return r;
}

// byte offset in a [rows][64]-bf16 tile (128B/row), 16B-chunk XOR swizzle
__device__ __forceinline__ int swz64(int row, int col) {
  return row * 128 + ((((col >> 3) ^ (row & 7)) << 4) | ((col & 7) << 1));
}

// ---------------- transpose + fp32->bf16 convert: in [K][N] -> out [N][K] ----
__global__ __launch_bounds__(256) void transpose_conv(const float* __restrict__ in,
    u16* __restrict__ out, int K, int N) {
  __shared__ float tile[32][33];
  size_t zo = (size_t)blockIdx.z * K * N;
  const float* inp = in + zo;
  u16* outp = out + zo;
  int n0 = blockIdx.x * 32, k0 = blockIdx.y * 32;
  int tx = threadIdx.x & 31, ty = threadIdx.x >> 5;
  #pragma unroll
  for (int r = ty; r < 32; r += 8) tile[r][tx] = inp[(size_t)(k0 + r) * N + n0 + tx];
  __syncthreads();
  #pragma unroll
  for (int r = ty; r < 32; r += 8) outp[(size_t)(n0 + r) * K + k0 + tx] = f2bf(tile[tx][r]);
}

// ---------------- fused 5-shift patchify + LayerNorm(3840) -> bf16 ----------
__global__ __launch_bounds__(256) void patch_ln(const float* __restrict__ x,
    const float* __restrict__ g, const float* __restrict__ bsh, u16* __restrict__ out,
    int t0) {
  int t = t0 + blockIdx.x;
  int tid = threadIdx.x;
  u16* orow = out + (size_t)blockIdx.x * 3840;
  if (t >= MROWS) {
    #pragma unroll
    for (int j = 0; j < 15; ++j) orow[tid + j * 256] = 0;  // bf16 zero
    return;
  }
  int bimg = t / NTOK, n = t % NTOK;
  int gy = n / GRID_H, gx = n % GRID_H;
  float vals[15];
  float s1 = 0.f, s2 = 0.f;
  #pragma unroll
  for (int j = 0; j < 15; ++j) {
    int cout = tid + j * 256;
    int s = cout / 768, rem = cout % 768;
    int c = rem / 256, rem2 = rem % 256;
    int py = rem2 / 16, px = rem2 % 16;
    int dy = (s == 1 ? 8 : 0) - (s == 2 ? 8 : 0);
    int dx = (s == 3 ? 8 : 0) - (s == 4 ? 8 : 0);
    int Y = gy * 16 + py - dy;
    int X = gx * 16 + px - dx;
    float v = 0.f;
    if (Y >= 0 && Y < 464 && X >= 0 && X < 464)
      v = x[(((size_t)bimg * 3 + c) * 464 + Y) * 464 + X];
    vals[j] = v;
    s1 += v; s2 += v * v;
  }
  #pragma unroll
  for (int m = 1; m < 64; m <<= 1) { s1 += __shfl_xor(s1, m); s2 += __shfl_xor(s2, m); }
  __shared__ float ws1[4], ws2[4];
  int wid = tid >> 6;
  if ((tid & 63) == 0) { ws1[wid] = s1; ws2[wid] = s2; }
  __syncthreads();
  s1 = ws1[0] + ws1[1] + ws1[2] + ws1[3];
  s2 = ws2[0] + ws2[1] + ws2[2] + ws2[3];
  float mean = s1 * (1.f / 3840.f);
  float var = s2 * (1.f / 3840.f) - mean * mean;
  float rs = rsqrtf(var + 1e-5f);
  #pragma unroll
  for (int j = 0; j < 15; ++j) {
    int cout = tid + j * 256;
    orow[cout] = f2bf((vals[j] - mean) * rs * g[cout] + bsh[cout]);
  }
}

// ---------------- LayerNorm(384) fp32 -> bf16 (packed MP rows) ---------------
__global__ __launch_bounds__(256) void ln384(const float* __restrict__ h,
    const float* __restrict__ g, const float* __restrict__ bsh, u16* __restrict__ y) {
  int row = blockIdx.x * 4 + (threadIdx.x >> 6);
  int lane = threadIdx.x & 63;
  const float* hr = h + (size_t)row * E_;
  float v[6];
  float s1 = 0.f;
  #pragma unroll
  for (int j = 0; j < 6; ++j) { v[j] = hr[lane + j * 64]; s1 += v[j]; }
  #pragma unroll
  for (int m = 1; m < 64; m <<= 1) s1 += __shfl_xor(s1, m);
  float mean = s1 * (1.f / 384.f);
  float s2 = 0.f;
  #pragma unroll
  for (int j = 0; j < 6; ++j) { float d = v[j] - mean; s2 += d * d; }
  #pragma unroll
  for (int m = 1; m < 64; m <<= 1) s2 += __shfl_xor(s2, m);
  float rs = rsqrtf(s2 * (1.f / 384.f) + 1e-5f);
  u16* yr = y + (size_t)row * E_;
  #pragma unroll
  for (int j = 0; j < 6; ++j) {
    int c = lane + j * 64;
    yr[c] = f2bf((v[j] - mean) * rs * g[c] + bsh[c]);
  }
}

// ---------------- LayerNorm(384) -> 896-padded bf16 (zeros on pad rows) ------
__global__ __launch_bounds__(256) void ln384p(const float* __restrict__ h,
    const float* __restrict__ g, const float* __restrict__ bsh, u16* __restrict__ yp) {
  int rowp = blockIdx.x * 4 + (threadIdx.x >> 6);
  int lane = threadIdx.x & 63;
  int bg = rowp / 896, tk = rowp - bg * 896;
  u16* yr = yp + (size_t)rowp * E_;
  if (tk >= NTOK) {
    #pragma unroll
    for (int j = 0; j < 6; ++j) yr[lane + j * 64] = 0;
    return;
  }
  const float* hr = h + (size_t)(bg * NTOK + tk) * E_;
  float v[6];
  float s1 = 0.f;
  #pragma unroll
  for (int j = 0; j < 6; ++j) { v[j] = hr[lane + j * 64]; s1 += v[j]; }
  #pragma unroll
  for (int m = 1; m < 64; m <<= 1) s1 += __shfl_xor(s1, m);
  float mean = s1 * (1.f / 384.f);
  float s2 = 0.f;
  #pragma unroll
  for (int j = 0; j < 6; ++j) { float d = v[j] - mean; s2 += d * d; }
  #pragma unroll
  for (int m = 1; m < 64; m <<= 1) s2 += __shfl_xor(s2, m);
  float rs = rsqrtf(s2 * (1.f / 384.f) + 1e-5f);
  #pragma unroll
  for (int j = 0; j < 6; ++j) {
    int c = lane + j * 64;
    yr[c] = f2bf((v[j] - mean) * rs * g[c] + bsh[c]);
  }
}

// ---------------- bf16 MFMA GEMM, min-2-phase pipelined (T3+T4) --------------
// EPI: 1 = bf16 gelu(acc+bias), LDS-staged coalesced out; 2 = f32 acc+bias;
//      3 = resid[m][n] += lscale[n]*(acc+bias[n]);
//      4 = outf[m][n] = resid[m][n] + lscale[n]*(acc+bias[n]) (final, m<MROWS)
// BK: 64 (8-chunk swizzle) or 32 (4-chunk swizzle, halves LDS for occupancy)
template<int EPI, int TM, int BK>
__global__ __launch_bounds__(256) void gemm_bt(
    const u16* __restrict__ A, const u16* __restrict__ BT,
    int N, int K,
    const float* __restrict__ bias, const float* __restrict__ lscale,
    float* __restrict__ resid, u16* __restrict__ outb, float* __restrict__ outf) {
  constexpr int MI = TM / 32;
  constexpr int BUF = (TM + 128) * BK;              // shorts per buffer
  constexpr int SM1 = 2 * BUF * 2;
  constexpr int SM2 = (EPI == 1) ? TM * 136 * 2 : 0;
  constexpr int SMEM = SM1 > SM2 ? SM1 : SM2;
  __shared__ alignas(16) char smem[SMEM];
  short* As = (short*)smem;
  // bijective XCD swizzle (m204)
  const int gx = gridDim.x;
  const int nwg = gx * gridDim.y;
  int L = blockIdx.x + blockIdx.y * gx;
  int q8 = nwg >> 3, r8 = nwg & 7, xcd = L & 7, pos = L >> 3;
  int L2 = (xcd < r8 ? xcd * (q8 + 1) : r8 * (q8 + 1) + (xcd - r8) * q8) + pos;
  const int m0 = (L2 / gx) * TM, n0 = (L2 % gx) * 128;
  const int tid = threadIdx.x;
  const int lane = tid & 63, wid = tid >> 6;
  const int wm = wid >> 1, wn = wid & 1;
  f32x4 acc[MI][4] = {};
  const int nkt = K / BK;

  auto stage = [&](int b, int kt) {
    short* Ab = As + b * BUF;
    short* Bb = Ab + TM * BK;
    const int k0 = kt * BK;
    if constexpr (BK == 64) {
      const int rowl = lane >> 3;
      const int colc = (((lane & 7) ^ (rowl & 7)) << 3);
      #pragma unroll
      for (int i = 0; i < TM / 32; ++i) {
        int chunk = i * 4 + wid;
        const u16* ga = A + (size_t)(m0 + chunk * 8 + rowl) * K + k0 + colc;
        __builtin_amdgcn_global_load_lds((const __attribute__((address_space(1))) void*)ga,
            (__attribute__((address_space(3))) void*)(Ab + (chunk << 9)), 16, 0, 0);
      }
      #pragma unroll
      for (int i = 0; i < 4; ++i) {
        int chunk = i * 4 + wid;
        const u16* gb = BT + (size_t)(n0 + chunk * 8 + rowl) * K + k0 + colc;
        __builtin_amdgcn_global_load_lds((const __attribute__((address_space(1))) void*)gb,
            (__attribute__((address_space(3))) void*)(Bb + (chunk << 9)), 16, 0, 0);
      }
    } else {
      const int rowl = lane >> 2;                 // 16 rows per wave-slab
      const int colc = (((lane & 3) ^ (rowl & 3)) << 3);
      #pragma unroll
      for (int i = 0; i < TM / 64; ++i) {
        int rbase = i * 64 + wid * 16;
        const u16* ga = A + (size_t)(m0 + rbase + rowl) * K + k0 + colc;
        __builtin_amdgcn_global_load_lds((const __attribute__((address_space(1))) void*)ga,
            (__attribute__((address_space(3))) void*)(Ab + rbase * 32), 16, 0, 0);
      }
      #pragma unroll
      for (int i = 0; i < 2; ++i) {
        int rbase = i * 64 + wid * 16;
        const u16* gb = BT + (size_t)(n0 + rbase + rowl) * K + k0 + colc;
        __builtin_amdgcn_global_load_lds((const __attribute__((address_space(1))) void*)gb,
            (__attribute__((address_space(3))) void*)(Bb + rbase * 32), 16, 0, 0);
      }
    }
  };

  const int lg = lane >> 4;
  stage(0, 0);
  for (int kt = 0; kt < nkt; ++kt) {
    const int cur = kt & 1;
    if (kt + 1 < nkt) {
      stage(cur ^ 1, kt + 1);
      // wait own current-tile loads (allow next tile's NL in flight)
      if constexpr (BK == 64) {
        if constexpr (TM == 128) asm volatile("s_waitcnt vmcnt(8)" ::: "memory");
        else                     asm volatile("s_waitcnt vmcnt(6)" ::: "memory");
      } else {
        if constexpr (TM == 128) asm volatile("s_waitcnt vmcnt(4)" ::: "memory");
        else                     asm volatile("s_waitcnt vmcnt(3)" ::: "memory");
      }
    } else {
      asm volatile("s_waitcnt vmcnt(0)" ::: "memory");
    }
    __builtin_amdgcn_s_barrier();       // all waves' current tile complete
    __builtin_amdgcn_sched_barrier(0);
    short* Ab = As + cur * BUF;
    short* Bb = Ab + TM * BK;
    #pragma unroll
    for (int kk = 0; kk < BK / 32; ++kk) {
      short8 a[MI], bfr[4];
      #pragma unroll
      for (int mi = 0; mi < MI; ++mi) {
        int ra = wm * (TM / 2) + mi * 16 + (lane & 15);
        int off = (BK == 64) ? ((((kk << 2) | lg) ^ (ra & 7)) << 3)
                             : ((lg ^ (ra & 3)) << 3);
        a[mi] = *(const short8*)(Ab + ra * BK + off);
      }
      #pragma unroll
      for (int nj = 0; nj < 4; ++nj) {
        int rb = wn * 64 + nj * 16 + (lane & 15);
        int off = (BK == 64) ? ((((kk << 2) | lg) ^ (rb & 7)) << 3)
                             : ((lg ^ (rb & 3)) << 3);
        bfr[nj] = *(const short8*)(Bb + rb * BK + off);
      }
      #pragma unroll
      for (int mi = 0; mi < MI; ++mi)
        #pragma unroll
        for (int nj = 0; nj < 4; ++nj)
          acc[mi][nj] = __builtin_amdgcn_mfma_f32_16x16x32_bf16(a[mi], bfr[nj], acc[mi][nj], 0, 0, 0);
    }
    __builtin_amdgcn_s_barrier();       // reads of 'cur' done before its overwrite
  }
  const int rrow = (lane >> 4) << 2;
  const int ccol = lane & 15;
  if (EPI == 1) {
    // stage C in LDS, write coalesced full rows
    u16* Cs = (u16*)smem;
    __syncthreads();
    #pragma unroll
    for (int mi = 0; mi < MI; ++mi)
      #pragma unroll
      for (int nj = 0; nj < 4; ++nj) {
        int cc = wn * 64 + nj * 16 + ccol;
        float bi = bias[n0 + cc];
        #pragma unroll
        for (int r = 0; r < 4; ++r) {
          int cr = wm * (TM / 2) + mi * 16 + rrow + r;
          Cs[cr * 136 + cc] = f2bf(gelu_exact(acc[mi][nj][r] + bi));
        }
      }
    __syncthreads();
    #pragma unroll
    for (int it = 0; it < TM / 16; ++it) {
      int idx = it * 256 + tid;
      int orow = idx >> 4, c = idx & 15;
      short8 v = *(const short8*)(Cs + orow * 136 + c * 8);
      *(short8*)(outb + (size_t)(m0 + orow) * N + n0 + c * 8) = v;
    }
    return;
  }
  #pragma unroll
  for (int mi = 0; mi < MI; ++mi)
    #pragma unroll
    for (int nj = 0; nj < 4; ++nj) {
      int gn = n0 + wn * 64 + nj * 16 + ccol;
      #pragma unroll
      for (int r = 0; r < 4; ++r) {
        int gm = m0 + wm * (TM / 2) + mi * 16 + rrow + r;
        float v = acc[mi][nj][r];
        if (EPI == 2) {
          outf[(size_t)gm * N + gn] = v + bias[gn];
        } else if (EPI == 3) {
          float* p = resid + (size_t)gm * N + gn;
          *p = *p + lscale[gn] * (v + bias[gn]);
        } else {
          if (gm < MROWS)
            outf[(size_t)gm * N + gn] =
                resid[(size_t)gm * N + gn] + lscale[gn] * (v + bias[gn]);
        }
      }
    }
}

// ---------------- qkv GEMM over padded-896 rows, BK=32 pipelined, swizzled out
__global__ __launch_bounds__(256) void gemm_qkv(
    const u16* __restrict__ A, const u16* __restrict__ BT,
    u16* __restrict__ Qp, u16* __restrict__ Kp, u16* __restrict__ Vp) {
  const int K = 384;
  constexpr int BUF = 256 * 32;                    // shorts per buffer (BK=32)
  constexpr int SM1 = 2 * BUF * 2;                 // 32KB staging dbuf
  constexpr int SM2 = 128 * 136 * 2;               // 34.8KB Cs epilogue
  constexpr int SMEM = SM1 > SM2 ? SM1 : SM2;
  __shared__ alignas(16) char smem[SMEM];
  short* As = (short*)smem;
  // XCD swizzle over 1008 blocks (1008 = 8*126)
  int L = blockIdx.x + blockIdx.y * 9;
  int L2 = (L & 7) * 126 + (L >> 3);
  const int m0 = (L2 / 9) * 128, n0 = (L2 % 9) * 128;
  const int tid = threadIdx.x;
  const int lane = tid & 63, wid = tid >> 6;
  const int wm = wid >> 1, wn = wid & 1;
  f32x4 acc[4][4] = {};

  auto stage = [&](int b, int kt) {
    short* Ab = As + b * BUF;
    short* Bb = Ab + 128 * 32;
    const int k0 = kt * 32;
    const int rowl = lane >> 2;                    // 16 rows per wave-slab
    const int colc = (((lane & 3) ^ (rowl & 3)) << 3);
    #pragma unroll
    for (int i = 0; i < 2; ++i) {
      int rbase = i * 64 + wid * 16;
      const u16* ga = A + (size_t)(m0 + rbase + rowl) * K + k0 + colc;
      __builtin_amdgcn_global_load_lds((const __attribute__((address_space(1))) void*)ga,
          (__attribute__((address_space(3))) void*)(Ab + rbase * 32), 16, 0, 0);
      const u16* gb = BT + (size_t)(n0 + rbase + rowl) * K + k0 + colc;
      __builtin_amdgcn_global_load_lds((const __attribute__((address_space(1))) void*)gb,
          (__attribute__((address_space(3))) void*)(Bb + rbase * 32), 16, 0, 0);
    }
  };

  const int lg = lane >> 4;
  stage(0, 0);
  for (int kt = 0; kt < 12; ++kt) {
    const int cur = kt & 1;
    if (kt + 1 < 12) {
      stage(cur ^ 1, kt + 1);
      asm volatile("s_waitcnt vmcnt(4)" ::: "memory");
    } else {
      asm volatile("s_waitcnt vmcnt(0)" ::: "memory");
    }
    __builtin_amdgcn_s_barrier();
    __builtin_amdgcn_sched_barrier(0);
    short* Ab = As + cur * BUF;
    short* Bb = Ab + 128 * 32;
    short8 a[4], bfr[4];
    #pragma unroll
    for (int mi = 0; mi < 4; ++mi) {
      int ra = wm * 64 + mi * 16 + (lane & 15);
      a[mi] = *(const short8*)(Ab + ra * 32 + ((lg ^ (ra & 3)) << 3));
    }
    #pragma unroll
    for (int nj = 0; nj < 4; ++nj) {
      int rb = wn * 64 + nj * 16 + (lane & 15);
      bfr[nj] = *(const short8*)(Bb + rb * 32 + ((lg ^ (rb & 3)) << 3));
    }
    #pragma unroll
    for (int mi = 0; mi < 4; ++mi)
      #pragma unroll
      for (int nj = 0; nj < 4; ++nj)
        acc[mi][nj] = __builtin_amdgcn_mfma_f32_16x16x32_bf16(a[mi], bfr[nj], acc[mi][nj], 0, 0, 0);
    __builtin_amdgcn_s_barrier();
  }
  // epilogue: stage in LDS ([tok][col] for Q/K, transposed [col][tok] for V)
  const int seg = n0 / 384;                 // 0=Q 1=K 2=V (block-uniform)
  const int h0 = (n0 - seg * 384) >> 6;     // head pair base: 0,2,4
  const int bg = m0 / 896;
  const int tk0 = m0 - bg * 896;            // 0..768, 64-tile aligned
  const int rrow = (lane >> 4) << 2;
  const int ccol = lane & 15;
  u16* Cs = (u16*)smem;
  __syncthreads();
  #pragma unroll
  for (int mi = 0; mi < 4; ++mi)
    #pragma unroll
    for (int nj = 0; nj < 4; ++nj) {
      int cc = wn * 64 + nj * 16 + ccol;
      #pragma unroll
      for (int r = 0; r < 4; ++r) {
        int cr = wm * 64 + mi * 16 + rrow + r;
        u16 bv = f2bf(acc[mi][nj][r]);
        if (seg == 2) Cs[cc * 136 + cr] = bv;
        else          Cs[cr * 136 + cc] = bv;
      }
    }
  __syncthreads();
  // write out 256 rows x 128B, full-line short8 stores
  #pragma unroll
  for (int i = 0; i < 8; ++i) {
    int idx = i * 256 + tid;
    int c = idx & 7;                 // 16B chunk within 128B row
    int orow = idx >> 3;             // 0..255
    int hs = orow >> 7;              // head select
    int rl = orow & 127;
    size_t bh = (size_t)(bg * 6 + h0 + hs);
    if (seg == 2) {
      int tile_l = rl >> 6, hd = rl & 63;
      short8 v = *(const short8*)(Cs + (hs * 64 + hd) * 136 + tile_l * 64 + c * 8);
      int tile = (tk0 >> 6) + tile_l;
      *(short8*)(Vp + bh * 57344 + tile * 4096 + hd * 64 + ((c ^ (hd & 7)) << 3)) = v;
    } else {
      short8 v = *(const short8*)(Cs + rl * 136 + hs * 64 + c * 8);
      if (seg == 0) {
        *(short8*)(Qp + (bh * 896 + tk0 + rl) * 64 + c * 8) = v;
      } else {
        int tok = tk0 + rl;
        *(short8*)(Kp + bh * 57344 + (tok >> 6) * 4096 + (tok & 63) * 64 + ((c ^ (tok & 7)) << 3)) = v;
      }
    }
  }
}

// ---------------- single-pass flash attention, 8 waves / 128 q-rows ----------
__global__ __launch_bounds__(512) void attn_sp(const u16* __restrict__ Qp,
    const u16* __restrict__ Kp, const u16* __restrict__ Vp,
    const float* __restrict__ temp_d, const float* __restrict__ locw_d,
    u16* __restrict__ ob) {
  // 1D grid = hardware dispatch order; bijective XCD swizzle: 672 = 8*84.
  int Lw = blockIdx.x;
  int L2 = (Lw & 7) * 84 + (Lw >> 3);
  const int bh = L2 / 7, qp = L2 % 7;       // qp = 128-row q-block
  const int hh = bh % NH_;
  const int tid = threadIdx.x, lane = tid & 63, w = tid >> 6;   // w in [0,8)
  const int lg = lane >> 4, lc = lane & 15;
  const float LOG2E = 1.44269504088896f;
  const float scale = __expf(temp_d[hh]) * LOG2E;   // exp2-domain
  const float lwh = locw_d[hh] * LOG2E * -0.5f;

  __shared__ alignas(16) char ktl[2][8192];       // K tiles [tok][hd], swizzled, dbuf
  __shared__ alignas(16) char vtl[2][8192];       // V^T tiles [hd][tok], swizzled, dbuf
  __shared__ alignas(16) char pl[8][2048];        // per-wave P [q][tok], swizzled
  __shared__ float yx2[896 * 2];                  // token coords (y,x)

  for (int j = tid; j < 896; j += 512) {
    unsigned jc = j < NTOK ? (unsigned)j : (NTOK - 1);
    yx2[j * 2]     = (float)(jc / 29u) * (1.f / 28.f);
    yx2[j * 2 + 1] = (float)(jc % 29u) * (1.f / 28.f);
  }

  // Q fragments from head-contiguous Qp (this wave's 16-row slice of 128)
  const char* qb = (const char*)(Qp + ((size_t)bh * 896 + qp * 128) * 64);
  short8 qf0 = *(const short8*)(qb + (w * 16 + lc) * 128 + lg * 16);
  short8 qf1 = *(const short8*)(qb + (w * 16 + lc) * 128 + 64 + lg * 16);

  const char* kbase = (const char*)Kp + (size_t)bh * 14 * 8192;
  const char* vbase = (const char*)Vp + (size_t)bh * 14 * 8192;

  // staging: 8 waves cover 8KB each of K and V (1 load per tensor per thread)
  auto stage = [&](int b, int kt) {
    int off = w * 1024;
    __builtin_amdgcn_global_load_lds(
        (const __attribute__((address_space(1))) void*)(kbase + kt * 8192 + off + lane * 16),
        (__attribute__((address_space(3))) void*)(ktl[b] + off), 16, 0, 0);
    __builtin_amdgcn_global_load_lds(
        (const __attribute__((address_space(1))) void*)(vbase + kt * 8192 + off + lane * 16),
        (__attribute__((address_space(3))) void*)(vtl[b] + off), 16, 0, 0);
  };

  f32x4 of[4] = {};
  float mrow[4], psum[4];
  #pragma unroll
  for (int r = 0; r < 4; ++r) { mrow[r] = -3e38f; psum[r] = 0.f; }

  stage(0, 0);
  asm volatile("s_waitcnt vmcnt(0)" ::: "memory");
  __syncthreads();

  // per-row coord weights (row-const lwh*|q|^2 dropped: softmax-invariant)
  float qyw[4], qxw[4];
  #pragma unroll
  for (int r = 0; r < 4; ++r) {
    int iq = qp * 128 + w * 16 + (lg << 2) + r;     // <= 895
    qyw[r] = -2.f * lwh * yx2[iq * 2];
    qxw[r] = -2.f * lwh * yx2[iq * 2 + 1];
  }

  for (int kt = 0; kt < 14; ++kt) {
    const int b = kt & 1;
    if (kt < 13) stage(b ^ 1, kt + 1);  // issue next-tile loads early (T14)

    const char* kb = ktl[b];
    const char* vb = vtl[b];
    f32x4 sf[4];
    __builtin_amdgcn_s_setprio(1);
    #pragma unroll
    for (int nt = 0; nt < 4; ++nt) {
      short8 kf0 = *(const short8*)(kb + swz64(nt * 16 + lc, lg << 3));
      short8 kf1 = *(const short8*)(kb + swz64(nt * 16 + lc, 32 + (lg << 3)));
      f32x4 z = {0.f, 0.f, 0.f, 0.f};
      z = __builtin_amdgcn_mfma_f32_16x16x32_bf16(qf0, kf0, z, 0, 0, 0);
      z = __builtin_amdgcn_mfma_f32_16x16x32_bf16(qf1, kf1, z, 0, 0, 0);
      sf[nt] = z;
    }
    __builtin_amdgcn_s_setprio(0);

    const int jb = kt * 64;
    #pragma unroll
    for (int nt = 0; nt < 4; ++nt) {
      int j = jb + nt * 16 + lc;
      float jy = yx2[j * 2], jx = yx2[j * 2 + 1];
      float bc = lwh * (jy * jy + jx * jx);
      #pragma unroll
      for (int r = 0; r < 4; ++r) {
        float val = sf[nt][r] * scale + bc;
        val += qyw[r] * jy;
        val += qxw[r] * jx;
        sf[nt][r] = val;
      }
    }
    if (jb + 64 > NTOK) {               // tail tile only (uniform branch)
      #pragma unroll
      for (int nt = 0; nt < 4; ++nt) {
        if (jb + nt * 16 + lc >= NTOK) {
          sf[nt][0] = -3e38f; sf[nt][1] = -3e38f; sf[nt][2] = -3e38f; sf[nt][3] = -3e38f;
        }
      }
    }

    float lm[4];
    #pragma unroll
    for (int r = 0; r < 4; ++r)
      lm[r] = fmaxf(fmaxf(sf[0][r], sf[1][r]), fmaxf(sf[2][r], sf[3][r]));
    bool trig = (lm[0] > mrow[0] + 12.f) | (lm[1] > mrow[1] + 12.f) |
                (lm[2] > mrow[2] + 12.f) | (lm[3] > mrow[3] + 12.f);
    if (__any(trig)) {
      #pragma unroll
      for (int r = 0; r < 4; ++r) {
        float tm = lm[r];
        #pragma unroll
        for (int m = 1; m < 16; m <<= 1) tm = fmaxf(tm, __shfl_xor(tm, m));
        float mnew = fmaxf(mrow[r], tm);
        float alpha = fexp2(mrow[r] - mnew);
        psum[r] *= alpha;
        of[0][r] *= alpha; of[1][r] *= alpha; of[2][r] *= alpha; of[3][r] *= alpha;
        mrow[r] = mnew;
      }
    }

    // exp2 + per-lane psum + packed bf16 conversion (v_cvt_pk, RNE)
    char* plw = pl[w];
    #pragma unroll
    for (int nt = 0; nt < 4; ++nt) {
      float p0 = fexp2(sf[nt][0] - mrow[0]);
      float p1 = fexp2(sf[nt][1] - mrow[1]);
      float p2 = fexp2(sf[nt][2] - mrow[2]);
      float p3 = fexp2(sf[nt][3] - mrow[3]);
      psum[0] += p0; psum[1] += p1; psum[2] += p2; psum[3] += p3;
      unsigned w01, w23;
      asm("v_cvt_pk_bf16_f32 %0, %1, %2" : "=v"(w01) : "v"(p0), "v"(p1));
      asm("v_cvt_pk_bf16_f32 %0, %1, %2" : "=v"(w23) : "v"(p2), "v"(p3));
      int col = nt * 16 + lc;
      *(u16*)(plw + swz64((lg << 2) + 0, col)) = (u16)w01;
      *(u16*)(plw + swz64((lg << 2) + 1, col)) = (u16)(w01 >> 16);
      *(u16*)(plw + swz64((lg << 2) + 2, col)) = (u16)w23;
      *(u16*)(plw + swz64((lg << 2) + 3, col)) = (u16)(w23 >> 16);
    }
    asm volatile("s_waitcnt lgkmcnt(0)" ::: "memory");
    __builtin_amdgcn_sched_barrier(0);
    short8 pa[2];
    #pragma unroll
    for (int t = 0; t < 2; ++t)
      pa[t] = *(const short8*)(plw + swz64(lc, t * 32 + (lg << 3)));

    __builtin_amdgcn_s_setprio(1);
    #pragma unroll
    for (int n2 = 0; n2 < 4; ++n2) {
      f32x4 accv = of[n2];
      #pragma unroll
      for (int t = 0; t < 2; ++t) {
        short8 vf = *(const short8*)(vb + swz64(n2 * 16 + lc, t * 32 + (lg << 3)));
        accv = __builtin_amdgcn_mfma_f32_16x16x32_bf16(pa[t], vf, accv, 0, 0, 0);
      }
      of[n2] = accv;
    }
    __builtin_amdgcn_s_setprio(0);

    if (kt < 13) {
      // next tile ready (own loads done) + all my LDS reads of buf b sampled
      asm volatile("s_waitcnt vmcnt(0) lgkmcnt(0)" ::: "memory");
      __builtin_amdgcn_sched_barrier(0);
      __builtin_amdgcn_s_barrier();
    }
  }

  // final: per-row sum reduce (16 lanes) + normalized output
  const int bimg = bh / NH_;
  #pragma unroll
  for (int r = 0; r < 4; ++r) {
    float s = psum[r];
    #pragma unroll
    for (int m = 1; m < 16; m <<= 1) s += __shfl_xor(s, m);
    int iq = qp * 128 + w * 16 + (lg << 2) + r;
    if (iq < NTOK) {
      float rl = 1.f / s;
      #pragma unroll
      for (int n2 = 0; n2 < 4; ++n2)
        ob[((size_t)(bimg * NTOK + iq)) * E_ + hh * 64 + n2 * 16 + lc] =
            f2bf(of[n2][r] * rl);
    }
  }
}

extern "C" void kernel_launch(void* const* d_in, const int* in_sizes, int n_in,
                              void* d_out, int out_size, void* d_ws, size_t ws_size,
                              hipStream_t stream) {
  const float* x      = (const float*)d_in[0];
  const float* tok_ng = (const float*)d_in[1];
  const float* tok_nb = (const float*)d_in[2];
  const float* tok_w1 = (const float*)d_in[3];
  const float* tok_b1 = (const float*)d_in[4];
  const float* tok_w2 = (const float*)d_in[5];
  const float* tok_b2 = (const float*)d_in[6];
  const float* ln1_g  = (const float*)d_in[7];
  const float* ln1_b  = (const float*)d_in[8];
  const float* w_qkv  = (const float*)d_in[9];
  const float* temp   = (const float*)d_in[10];
  const float* loc_w  = (const float*)d_in[11];
  const float* w_proj = (const float*)d_in[12];
  const float* b_proj = (const float*)d_in[13];
  const float* ls1    = (const float*)d_in[14];
  const float* ln2_g  = (const float*)d_in[15];
  const float* ln2_b  = (const float*)d_in[16];
  const float* ff_w1  = (const float*)d_in[17];
  const float* ff_b1  = (const float*)d_in[18];
  const float* ff_w2  = (const float*)d_in[19];
  const float* ff_b2  = (const float*)d_in[20];
  const float* ls2    = (const float*)d_in[21];
  float* out = (float*)d_out;

  char* ws = (char*)d_ws;
  size_t off = 0;
  auto alloc = [&](size_t bytes) -> void* {
    void* p = ws + off; off += (bytes + 255) & ~(size_t)255; return p;
  };
  // weights (persistent per launch)
  u16* w1T   = (u16*)alloc(768UL * 3840 * 2);
  u16* w2T   = (u16*)alloc(384UL * 768 * 2);
  u16* qkvT  = (u16*)alloc(8UL * 1152 * 384 * 2);
  u16* projT = (u16*)alloc(8UL * 384 * 384 * 2);
  u16* f1T   = (u16*)alloc(8UL * 1536 * 384 * 2);
  u16* f2T   = (u16*)alloc(8UL * 384 * 1536 * 2);
  // persistent activation
  float* h   = (float*)alloc((size_t)MP * 384 * 4);
  // regB: h1 (embed) OR { ypad/yff | ob } (blocks)
  char* regB = (char*)alloc(22500000);
  u16* h1   = (u16*)regB;                               // [MP][768] bf16 (embed)
  u16* ypad = (u16*)regB;                               // [MQ][384] = 11.01MB
  u16* yff  = (u16*)regB;                               // [MP][384] (ln2 out)
  u16* ob   = (u16*)(regB + 11010048);                  // [MP][384] = 10.42MB
  // regA: Xlnc (embed) OR Qp/Kp/Vp (attn) OR f1b (ff)
  char* regA = (char*)alloc((size_t)MP * 1536 * 2);
  u16* Xlnc = (u16*)regA;
  u16* Qp   = (u16*)regA;                               // 96*896*64*2  = 11.0MB
  u16* Kp   = (u16*)(regA + 11010048);                  // 96*14*8192   = 11.0MB
  u16* Vp   = (u16*)(regA + 22020096);                  // 11.0MB (33MB <= 41.7MB)
  u16* f1b  = (u16*)regA;
  (void)in_sizes; (void)n_in; (void)out_size;

  if (off > ws_size) return;  // diagnostic: leaves d_out untouched -> absmax ~2.5

  // weight transposes (fp32 [K][N] -> bf16 [N][K])
  transpose_conv<<<dim3(24, 120, 1), 256, 0, stream>>>(tok_w1, w1T, 3840, 768);
  transpose_conv<<<dim3(12, 24, 1), 256, 0, stream>>>(tok_w2, w2T, 768, 384);
  transpose_conv<<<dim3(36, 12, 8), 256, 0, stream>>>(w_qkv, qkvT, 384, 1152);
  transpose_conv<<<dim3(12, 12, 8), 256, 0, stream>>>(w_proj, projT, 384, 384);
  transpose_conv<<<dim3(48, 12, 8), 256, 0, stream>>>(ff_w1, f1T, 384, 1536);
  transpose_conv<<<dim3(12, 48, 8), 256, 0, stream>>>(ff_w2, f2T, 1536, 384);

  // patch embed + LN(3840) + first GEMM, chunked through Xlnc
  // tok1 at TM=64: grid 6 x rows/64 -> 2x blocks (grid-limited kernel)
  for (int m = 0; m < MP; m += CM) {
    int rows = MP - m; if (rows > CM) rows = CM;
    patch_ln<<<rows, 256, 0, stream>>>(x, tok_ng, tok_nb, Xlnc, m);
    gemm_bt<1, 64, 64><<<dim3(6, rows / 64), 256, 0, stream>>>(Xlnc, w1T, 768, 3840,
        tok_b1, nullptr, nullptr, h1 + (size_t)m * 768, nullptr);
  }
  gemm_bt<2, 64, 64><<<dim3(3, MP / 64), 256, 0, stream>>>(h1, w2T, 384, 768, tok_b2,
      nullptr, nullptr, nullptr, h);

  for (int d = 0; d < 8; ++d) {
    ln384p<<<MQ / 4, 256, 0, stream>>>(h, ln1_g + d * E_, ln1_b + d * E_, ypad);
    gemm_qkv<<<dim3(9, 112), 256, 0, stream>>>(ypad, qkvT + (size_t)d * 1152 * 384, Qp, Kp, Vp);
    attn_sp<<<672, 512, 0, stream>>>(Qp, Kp, Vp, temp + d * NH_, loc_w + d * NH_, ob);
    gemm_bt<3, 64, 64><<<dim3(3, MP / 64), 256, 0, stream>>>(ob, projT + (size_t)d * 384 * 384,
        384, 384, b_proj + d * E_, ls1 + d * E_, h, nullptr, nullptr);
    ln384<<<MP / 4, 256, 0, stream>>>(h, ln2_g + d * E_, ln2_b + d * E_, yff);
    gemm_bt<1, 128, 32><<<dim3(12, MP / 128), 256, 0, stream>>>(yff, f1T + (size_t)d * 1536 * 384,
        1536, 384, ff_b1 + d * 1536, nullptr, nullptr, f1b, nullptr);
    if (d < 7)
      gemm_bt<3, 64, 64><<<dim3(3, MP / 64), 256, 0, stream>>>(f1b, f2T + (size_t)d * 384 * 1536,
          384, 1536, ff_b2 + d * E_, ls2 + d * E_, h, nullptr, nullptr);
    else
      gemm_bt<4, 64, 64><<<dim3(3, MP / 64), 256, 0, stream>>>(f1b, f2T + (size_t)d * 384 * 1536,
          384, 1536, ff_b2 + d * E_, ls2 + d * E_, h, nullptr, out);
  }
}